// Round 14
// baseline (17120.526 us; speedup 1.0000x reference)
//
#include <hip/hip_runtime.h>
#include <math.h>

#define N_PTS 16384
#define M_CTR 4096
#define NS 16
#define CIN 64
#define COUT 128
#define CFEAT 67
#define CPB 4          // centers per block in passA
#define NCELL 4096     // 16x16x16 grid, Morton order
#define NTH 512        // FPS threads
#define PPT 32         // points per thread

typedef unsigned long long u64;

// ---------------- payload pair-merge: (a1>=a2)+coords U (b1>=b2)+coords ----------------
__device__ __forceinline__ void pmergeP(u64& a1, u64& a2,
                                        float& x1, float& y1, float& z1,
                                        float& x2, float& y2, float& z2,
                                        u64 b1, u64 b2,
                                        float dx1, float dy1, float dz1,
                                        float dx2, float dy2, float dz2)
{
    bool t = b1 > a1;
    u64 hi = t ? b1 : a1; float hx = t ? dx1 : x1, hy = t ? dy1 : y1, hz = t ? dz1 : z1;
    u64 lo = t ? a1 : b1; float lx = t ? x1 : dx1, ly = t ? y1 : dy1, lz = t ? z1 : dz1;
    bool u = b2 > a2;
    u64 m  = u ? b2 : a2; float mx = u ? dx2 : x2, my = u ? dy2 : y2, mz = u ? dz2 : z2;
    bool v = lo > m;
    a2 = v ? lo : m; x2 = v ? lx : mx; y2 = v ? ly : my; z2 = v ? lz : mz;
    a1 = hi; x1 = hx; y1 = hy; z1 = hz;
}

#define DPP_F(CTRL, x) __int_as_float(__builtin_amdgcn_update_dpp(0, __float_as_int(x), CTRL, 0xF, 0xF, false))

// top-2+coords merge toward lane 63 (old=0 identity: key 0 never selected)
#define SWEEP_STEP(CTRL) do { \
    unsigned _b1lo = (unsigned)__builtin_amdgcn_update_dpp(0, (int)(unsigned)k1, CTRL, 0xF, 0xF, false); \
    unsigned _b1hi = (unsigned)__builtin_amdgcn_update_dpp(0, (int)(unsigned)(k1>>32), CTRL, 0xF, 0xF, false); \
    unsigned _b2lo = (unsigned)__builtin_amdgcn_update_dpp(0, (int)(unsigned)k2, CTRL, 0xF, 0xF, false); \
    unsigned _b2hi = (unsigned)__builtin_amdgcn_update_dpp(0, (int)(unsigned)(k2>>32), CTRL, 0xF, 0xF, false); \
    u64 _b1 = ((u64)_b1hi << 32) | (u64)_b1lo; \
    u64 _b2 = ((u64)_b2hi << 32) | (u64)_b2lo; \
    float _d1x = DPP_F(CTRL, c1x), _d1y = DPP_F(CTRL, c1y), _d1z = DPP_F(CTRL, c1z); \
    float _d2x = DPP_F(CTRL, c2x), _d2y = DPP_F(CTRL, c2y), _d2z = DPP_F(CTRL, c2z); \
    pmergeP(k1, k2, c1x, c1y, c1z, c2x, c2y, c2z, _b1, _b2, _d1x, _d1y, _d1z, _d2x, _d2y, _d2z); \
} while (0)

#define SWEEP_ALL SWEEP_STEP(0x111); SWEEP_STEP(0x112); SWEEP_STEP(0x114); \
                  SWEEP_STEP(0x118); SWEEP_STEP(0x142); SWEEP_STEP(0x143)

// ---------------- init: counters ----------------
__global__ void init_kernel(int* __restrict__ cnt, int* __restrict__ fill)
{
    int i = blockIdx.x * blockDim.x + threadIdx.x;
    if (i < NCELL) { cnt[i] = 0; fill[i] = 0; }
}

// ---------------- cloud bbox (single block, deterministic) ----------------
__global__ __launch_bounds__(256) void bbox_kernel(const float* __restrict__ p,
                                                   float* __restrict__ gbb)
{
    int t = threadIdx.x, lane = t & 63, w = t >> 6;
    float mnx = 1e30f, mny = 1e30f, mnz = 1e30f;
    float mxx = -1e30f, mxy = -1e30f, mxz = -1e30f;
    for (int i = t; i < N_PTS; i += 256) {
        float x = p[i*3], y = p[i*3+1], z = p[i*3+2];
        mnx = fminf(mnx, x); mny = fminf(mny, y); mnz = fminf(mnz, z);
        mxx = fmaxf(mxx, x); mxy = fmaxf(mxy, y); mxz = fmaxf(mxz, z);
    }
    for (int m = 1; m < 64; m <<= 1) {
        mnx = fminf(mnx, __shfl_xor(mnx, m)); mny = fminf(mny, __shfl_xor(mny, m));
        mnz = fminf(mnz, __shfl_xor(mnz, m));
        mxx = fmaxf(mxx, __shfl_xor(mxx, m)); mxy = fmaxf(mxy, __shfl_xor(mxy, m));
        mxz = fmaxf(mxz, __shfl_xor(mxz, m));
    }
    __shared__ float s[4][6];
    if (lane == 0) { s[w][0]=mnx; s[w][1]=mny; s[w][2]=mnz; s[w][3]=mxx; s[w][4]=mxy; s[w][5]=mxz; }
    __syncthreads();
    if (t == 0) {
        gbb[0] = fminf(fminf(s[0][0], s[1][0]), fminf(s[2][0], s[3][0]));
        gbb[1] = fminf(fminf(s[0][1], s[1][1]), fminf(s[2][1], s[3][1]));
        gbb[2] = fminf(fminf(s[0][2], s[1][2]), fminf(s[2][2], s[3][2]));
        gbb[3] = fmaxf(fmaxf(s[0][3], s[1][3]), fmaxf(s[2][3], s[3][3]));
        gbb[4] = fmaxf(fmaxf(s[0][4], s[1][4]), fmaxf(s[2][4], s[3][4]));
        gbb[5] = fmaxf(fmaxf(s[0][5], s[1][5]), fmaxf(s[2][5], s[3][5]));
    }
}

// ---------------- assign points to 16^3 cells, MORTON order ----------------
__device__ __forceinline__ int part3_4(int v) {   // 4 bits -> bits 0,3,6,9
    return (v & 1) | ((v & 2) << 2) | ((v & 4) << 4) | ((v & 8) << 6);
}
__global__ void assign_kernel(const float* __restrict__ p, const float* __restrict__ gbb,
                              int* __restrict__ c_of, int* __restrict__ cnt)
{
    int i = blockIdx.x * blockDim.x + threadIdx.x;
    if (i >= N_PTS) return;
    float bx = gbb[0], by = gbb[1], bz = gbb[2];
    float sx = 15.9999f / fmaxf(gbb[3] - bx, 1e-20f);
    float sy = 15.9999f / fmaxf(gbb[4] - by, 1e-20f);
    float sz = 15.9999f / fmaxf(gbb[5] - bz, 1e-20f);
    float x = p[i*3], y = p[i*3+1], z = p[i*3+2];
    int ix = min(15, max(0, (int)((x - bx) * sx)));
    int iy = min(15, max(0, (int)((y - by) * sy)));
    int iz = min(15, max(0, (int)((z - bz) * sz)));
    int c = (part3_4(ix) << 2) | (part3_4(iy) << 1) | part3_4(iz);   // Morton
    c_of[i] = c;
    atomicAdd(&cnt[c], 1);
}

// ---------------- exclusive prefix over 4096 counts ----------------
__global__ __launch_bounds__(1024) void prefix_kernel(const int* __restrict__ cnt,
                                                      int* __restrict__ start)
{
    __shared__ int a[1024];
    int t = threadIdx.x;
    int c0 = cnt[4*t], c1 = cnt[4*t+1], c2 = cnt[4*t+2], c3 = cnt[4*t+3];
    int s = c0 + c1 + c2 + c3;
    a[t] = s; __syncthreads();
    for (int off = 1; off < 1024; off <<= 1) {
        int u = (t >= off) ? a[t - off] : 0;
        __syncthreads();
        a[t] += u;
        __syncthreads();
    }
    int ex = a[t] - s;
    start[4*t]   = ex;
    start[4*t+1] = ex + c0;
    start[4*t+2] = ex + c0 + c1;
    start[4*t+3] = ex + c0 + c1 + c2;
}

// ---------------- scatter into thread-transposed sorted layout ----------------
// sorted position j -> spT[(j&31)*512 + (j>>5)]  (thread t owns column t, rows 0..31)
__global__ void scatter_kernel(const float* __restrict__ p, const int* __restrict__ c_of,
                               const int* __restrict__ start, int* __restrict__ fill,
                               float4* __restrict__ spT)
{
    int i = blockIdx.x * blockDim.x + threadIdx.x;
    if (i >= N_PTS) return;
    int c = c_of[i];
    int j = start[c] + atomicAdd(&fill[c], 1);
    spT[(j & 31) * NTH + (j >> 5)] = make_float4(p[i*3], p[i*3+1], p[i*3+2], __int_as_float(i));
}

// ---------------- FPS: 1-barrier round, coords-payload reduce, Morton locality ----------------
__global__ __launch_bounds__(NTH) void fps_kernel(const float* __restrict__ p,
                                                  const float4* __restrict__ spT,
                                                  int* __restrict__ sel)
{
    __shared__ float distT[N_PTS];            // 64 KB, [k*512+t] -> conflict-free
    __shared__ u64 skw1[2][8], skw2[2][8];    // parity-double-buffered wave results
    __shared__ float skc[2][8][6];            // payload coords (c1xyz, c2xyz)

    const int t = threadIdx.x;
    const int lane = t & 63, wave = t >> 6;

    for (int i = t; i < N_PTS; i += NTH) distT[i] = 1e10f;

    // tight bbox over own 32 points (coalesced reads of column t)
    float bmnx = 1e30f, bmny = 1e30f, bmnz = 1e30f;
    float bmxx = -1e30f, bmxy = -1e30f, bmxz = -1e30f;
#pragma unroll 8
    for (int k = 0; k < PPT; ++k) {
        float4 P = spT[(k << 9) + t];
        bmnx = fminf(bmnx, P.x); bmny = fminf(bmny, P.y); bmnz = fminf(bmnz, P.z);
        bmxx = fmaxf(bmxx, P.x); bmxy = fmaxf(bmxy, P.y); bmxz = fmaxf(bmxz, P.z);
    }

    float tmax = 1e10f;
    u64 kc1 = 0ull, kc2 = 0ull;                       // cached own top-2
    float cc1x = 0.f, cc1y = 0.f, cc1z = 0.f;         // + coords
    float cc2x = 0.f, cc2y = 0.f, cc2z = 0.f;
    u64 wk1 = 0ull, wk2 = 0ull;                       // lane63: cached wave result
    float w1x = 0.f, w1y = 0.f, w1z = 0.f, w2x = 0.f, w2y = 0.f, w2z = 0.f;

    if (t == 0) sel[0] = 0;
    float q1x = p[0], q1y = p[1], q1z = p[2];
    float q2x = 0.f, q2y = 0.f, q2z = 0.f;
    bool two = false, first = true;
    int rpar = 0;
    __syncthreads();

    int it = 1;
    while (it < M_CTR) {
        // ---- phase A: prune (registers only) ----
        bool act;
        if (first) act = true;
        else {
            float cm = tmax * 1.00001f;
            float ddx = fmaxf(fmaxf(__fsub_rn(bmnx, q1x), __fsub_rn(q1x, bmxx)), 0.f);
            float ddy = fmaxf(fmaxf(__fsub_rn(bmny, q1y), __fsub_rn(q1y, bmxy)), 0.f);
            float ddz = fmaxf(fmaxf(__fsub_rn(bmnz, q1z), __fsub_rn(q1z, bmxz)), 0.f);
            float dm1 = __fadd_rn(__fadd_rn(__fmul_rn(ddx,ddx), __fmul_rn(ddy,ddy)),
                                  __fmul_rn(ddz,ddz));
            act = dm1 < cm;
            if (!act && two) {
                float ex = fmaxf(fmaxf(__fsub_rn(bmnx, q2x), __fsub_rn(q2x, bmxx)), 0.f);
                float ey = fmaxf(fmaxf(__fsub_rn(bmny, q2y), __fsub_rn(q2y, bmxy)), 0.f);
                float ez = fmaxf(fmaxf(__fsub_rn(bmnz, q2z), __fsub_rn(q2z, bmxz)), 0.f);
                float dm2 = __fadd_rn(__fadd_rn(__fmul_rn(ex,ex), __fmul_rn(ey,ey)),
                                      __fmul_rn(ez,ez));
                act = dm2 < cm;
            }
        }

        if (act) {
            // rescan own 32 points (coalesced spT, conflict-free distT)
            float nmax = -1.0f;
            u64 k1 = 0ull, k2 = 0ull;
            float p1x = 0.f, p1y = 0.f, p1z = 0.f, p2x = 0.f, p2y = 0.f, p2z = 0.f;
#pragma unroll 4
            for (int k = 0; k < PPT; ++k) {
                int a = (k << 9) + t;
                float4 P = spT[a];
                float D = distT[a];
                float dx = __fsub_rn(P.x, q1x), dy = __fsub_rn(P.y, q1y), dz = __fsub_rn(P.z, q1z);
                float d2 = __fadd_rn(__fadd_rn(__fmul_rn(dx,dx), __fmul_rn(dy,dy)),
                                     __fmul_rn(dz,dz));
                float nd = fminf(D, d2);
                if (two) {
                    float ex = __fsub_rn(P.x, q2x), ey = __fsub_rn(P.y, q2y), ez = __fsub_rn(P.z, q2z);
                    float e2 = __fadd_rn(__fadd_rn(__fmul_rn(ex,ex), __fmul_rn(ey,ey)),
                                         __fmul_rn(ez,ez));
                    nd = fminf(nd, e2);
                }
                distT[a] = nd;
                nmax = fmaxf(nmax, nd);
                u64 kk = ((u64)__float_as_uint(nd) << 32)
                       | (u64)(~(unsigned)__float_as_int(P.w));
                bool g1 = kk > k1;
                bool g2 = kk > k2;
                u64 nk2 = g1 ? k1 : (g2 ? kk : k2);
                float n2x = g1 ? p1x : (g2 ? P.x : p2x);
                float n2y = g1 ? p1y : (g2 ? P.y : p2y);
                float n2z = g1 ? p1z : (g2 ? P.z : p2z);
                k1 = g1 ? kk : k1;
                p1x = g1 ? P.x : p1x; p1y = g1 ? P.y : p1y; p1z = g1 ? P.z : p1z;
                k2 = nk2; p2x = n2x; p2y = n2y; p2z = n2z;
            }
            tmax = nmax;
            kc1 = k1; kc2 = k2;
            cc1x = p1x; cc1y = p1y; cc1z = p1z;
            cc2x = p2x; cc2y = p2y; cc2z = p2z;
        }

        // ---- wave-gated payload sweep (Morton -> few active waves late) ----
        unsigned long long wmask = __ballot(act);
        if (wmask != 0ull) {
            u64 k1 = kc1, k2 = kc2;
            float c1x = cc1x, c1y = cc1y, c1z = cc1z;
            float c2x = cc2x, c2y = cc2y, c2z = cc2z;
            SWEEP_ALL;
            if (lane == 63) {
                wk1 = k1; wk2 = k2;
                w1x = c1x; w1y = c1y; w1z = c1z;
                w2x = c2x; w2y = c2y; w2z = c2z;
            }
        }
        if (lane == 63) {   // always publish (fresh or cached) to current parity
            skw1[rpar][wave] = wk1; skw2[rpar][wave] = wk2;
            skc[rpar][wave][0] = w1x; skc[rpar][wave][1] = w1y; skc[rpar][wave][2] = w1z;
            skc[rpar][wave][3] = w2x; skc[rpar][wave][4] = w2y; skc[rpar][wave][5] = w2z;
        }
        __syncthreads();   // the ONLY barrier per round

        // ---- phase B: every thread redundantly merges the 8 wave pairs ----
        u64 A1 = skw1[rpar][0], A2 = skw2[rpar][0];
        float a1x = skc[rpar][0][0], a1y = skc[rpar][0][1], a1z = skc[rpar][0][2];
        float a2x = skc[rpar][0][3], a2y = skc[rpar][0][4], a2z = skc[rpar][0][5];
#pragma unroll
        for (int w = 1; w < 8; ++w) {
            pmergeP(A1, A2, a1x, a1y, a1z, a2x, a2y, a2z,
                    skw1[rpar][w], skw2[rpar][w],
                    skc[rpar][w][0], skc[rpar][w][1], skc[rpar][w][2],
                    skc[rpar][w][3], skc[rpar][w][4], skc[rpar][w][5]);
        }

        int nsel = 1;
        if (A2 != 0ull && it + 1 < M_CTR) {
            // exact accept: if s1's update provably leaves the global #2 key
            // unchanged, every other key can only drop below it.
            float dx = __fsub_rn(a2x, a1x), dy = __fsub_rn(a2y, a1y), dz = __fsub_rn(a2z, a1z);
            float d2b = __fadd_rn(__fadd_rn(__fmul_rn(dx,dx), __fmul_rn(dy,dy)),
                                  __fmul_rn(dz,dz));
            float db = __uint_as_float((unsigned)(A2 >> 32));
            if (d2b >= db) nsel = 2;
        }
        if (t == 0) {
            sel[it] = (int)(~(unsigned)(A1 & 0xFFFFFFFFull));
            if (nsel == 2) sel[it + 1] = (int)(~(unsigned)(A2 & 0xFFFFFFFFull));
        }
        q1x = a1x; q1y = a1y; q1z = a1z;
        two = (nsel == 2);
        if (two) { q2x = a2x; q2y = a2y; q2z = a2z; }
        first = false;
        it += nsel;
        rpar ^= 1;
    }
}

// ---------------- prep: pp2, gather n_p/n_n, write n_o ----------------
__global__ void prep_kernel(const float* __restrict__ p, const float* __restrict__ nrm,
                            const int* __restrict__ sel, float* __restrict__ pp2,
                            float* __restrict__ out)
{
    int i = blockIdx.x * blockDim.x + threadIdx.x;
    if (i < N_PTS) {
        float x = p[i*3], y = p[i*3+1], z = p[i*3+2];
        pp2[i] = __fadd_rn(__fadd_rn(__fmul_rn(x,x), __fmul_rn(y,y)), __fmul_rn(z,z));
    }
    if (i < M_CTR) {
        int j = sel[i];
        out[i*3+0] = p[j*3+0]; out[i*3+1] = p[j*3+1]; out[i*3+2] = p[j*3+2];
        out[12288 + i*3+0] = nrm[j*3+0];
        out[12288 + i*3+1] = nrm[j*3+1];
        out[12288 + i*3+2] = nrm[j*3+2];
    }
    if (i == 0) out[548864] = (float)M_CTR;   // n_o
}

// ---------------- kNN: one wave per center, per-lane sorted top-16 ----------------
__global__ __launch_bounds__(256) void knn_kernel(const float* __restrict__ p,
                                                  const float* __restrict__ pp2,
                                                  const float* __restrict__ np /* n_p */,
                                                  int* __restrict__ knn)
{
    const int lane = threadIdx.x & 63;
    const int wave = threadIdx.x >> 6;
    const int c = blockIdx.x * 4 + wave;

    float cx = np[c*3], cy = np[c*3+1], cz = np[c*3+2];
    float c2 = __fadd_rn(__fadd_rn(__fmul_rn(cx,cx), __fmul_rn(cy,cy)), __fmul_rn(cz,cz));

    float hd[16]; int hi[16];
#pragma unroll
    for (int k = 0; k < 16; ++k) { hd[k] = 1e30f; hi[k] = 0x7fffffff; }

    for (int t = 0; t < N_PTS/64; ++t) {
        int j = t*64 + lane;
        float px = p[j*3+0], py = p[j*3+1], pz = p[j*3+2];
        float dot = __fadd_rn(__fadd_rn(__fmul_rn(cx,px), __fmul_rn(cy,py)),
                              __fmul_rn(cz,pz));
        float d2  = __fsub_rn(__fadd_rn(c2, pp2[j]), __fmul_rn(2.0f, dot));
        if (d2 < hd[15]) {
#pragma unroll
            for (int k = 15; k >= 1; --k) {
                bool up   = d2 < hd[k-1];
                bool here = d2 < hd[k];
                hd[k] = up ? hd[k-1] : (here ? d2 : hd[k]);
                hi[k] = up ? hi[k-1] : (here ? j  : hi[k]);
            }
            if (d2 < hd[0]) { hd[0] = d2; hi[0] = j; }
        }
    }

    for (int r = 0; r < 16; ++r) {
        float wv = hd[0]; int wi = hi[0];
#pragma unroll
        for (int m = 1; m < 64; m <<= 1) {
            float ov = __shfl_xor(wv, m);
            int   oi = __shfl_xor(wi, m);
            bool b = (ov < wv) || (ov == wv && oi < wi);
            wv = b ? ov : wv; wi = b ? oi : wi;
        }
        if (hi[0] == wi) {
            knn[c*16 + r] = wi;
#pragma unroll
            for (int k = 0; k < 15; ++k) { hd[k] = hd[k+1]; hi[k] = hi[k+1]; }
            hd[15] = 1e30f; hi[15] = 0x7fffffff;
        }
    }
}

// ---------------- pass A: feat build + GEMM + stats + ymax/ymin ----------------
__global__ __launch_bounds__(128) void passA_kernel(const float* __restrict__ p,
                                                    const float* __restrict__ xf,
                                                    const float* __restrict__ W,
                                                    const int* __restrict__ knn,
                                                    const float* __restrict__ out /* n_p */,
                                                    float* __restrict__ ymax,
                                                    float* __restrict__ ymin,
                                                    float* __restrict__ partials)
{
    __shared__ float Wt[CFEAT][COUT];
    __shared__ float ft[CPB][NS][CFEAT];
    __shared__ float bsum[CPB][COUT], bssq[CPB][COUT];

    const int t = threadIdx.x;
    const int mbase = blockIdx.x * CPB;

    for (int c = 0; c < CFEAT; ++c) Wt[c][t] = W[t*CFEAT + c];

    {
        int r = t >> 1, half = t & 1;
        int ci = r >> 4, s = r & 15;
        int m = mbase + ci;
        int nb = knn[m*NS + s];
        if (half == 0) {
            ft[ci][s][0] = __fsub_rn(p[nb*3+0], out[m*3+0]);
            ft[ci][s][1] = __fsub_rn(p[nb*3+1], out[m*3+1]);
            ft[ci][s][2] = __fsub_rn(p[nb*3+2], out[m*3+2]);
        }
        for (int c = half*32; c < half*32 + 32; ++c)
            ft[ci][s][3+c] = xf[nb*CIN + c];
    }
    __syncthreads();

    const int ci = t >> 5, l = t & 31;
    float acc[NS][4];
#pragma unroll
    for (int s = 0; s < NS; ++s) { acc[s][0]=0.f; acc[s][1]=0.f; acc[s][2]=0.f; acc[s][3]=0.f; }

    for (int c = 0; c < CFEAT; ++c) {
        float w0 = Wt[c][l], w1 = Wt[c][l+32], w2 = Wt[c][l+64], w3 = Wt[c][l+96];
#pragma unroll
        for (int s = 0; s < NS; ++s) {
            float f = ft[ci][s][c];
            acc[s][0] = fmaf(f, w0, acc[s][0]);
            acc[s][1] = fmaf(f, w1, acc[s][1]);
            acc[s][2] = fmaf(f, w2, acc[s][2]);
            acc[s][3] = fmaf(f, w3, acc[s][3]);
        }
    }

    const int m = mbase + ci;
#pragma unroll
    for (int j = 0; j < 4; ++j) {
        int o = l + 32*j;
        float s = 0.f, q = 0.f, mx = -1e30f, mn = 1e30f;
#pragma unroll
        for (int sidx = 0; sidx < NS; ++sidx) {
            float v = acc[sidx][j];
            s += v; q = fmaf(v, v, q);
            mx = fmaxf(mx, v); mn = fminf(mn, v);
        }
        bsum[ci][o] = s;
        bssq[ci][o] = q;
        ymax[m*COUT + o] = mx;
        ymin[m*COUT + o] = mn;
    }
    __syncthreads();
    if (t < COUT) {
        float s = bsum[0][t] + bsum[1][t] + bsum[2][t] + bsum[3][t];
        float q = bssq[0][t] + bssq[1][t] + bssq[2][t] + bssq[3][t];
        partials[t*1024          + blockIdx.x] = s;
        partials[(COUT + t)*1024 + blockIdx.x] = q;
    }
}

// ---------------- BN stats reduce -> scale/shift ----------------
__global__ __launch_bounds__(256) void bnstat_kernel(const float* __restrict__ partials,
                                                     const float* __restrict__ gamma,
                                                     const float* __restrict__ beta,
                                                     float* __restrict__ scaleshift)
{
    __shared__ float red[256];
    int t = threadIdx.x;
    const float4* v4 = (const float4*)(partials + t*1024);
    float s = 0.f;
    for (int i = 0; i < 256; ++i) {
        float4 v = v4[i];
        s += v.x; s += v.y; s += v.z; s += v.w;
    }
    red[t] = s;
    __syncthreads();
    if (t < COUT) {
        const float inv = 1.0f / 65536.0f;
        float mean = red[t] * inv;
        float var  = red[COUT + t] * inv - mean*mean;
        float rstd = rsqrtf(var + 1e-5f);
        float g = gamma[t] * rstd;
        scaleshift[t]        = g;
        scaleshift[COUT + t] = beta[t] - mean * g;
    }
}

// ---------------- final: BN apply + ReLU on the pooled extreme ----------------
__global__ void final_kernel(float* __restrict__ y,
                             const float* __restrict__ ymin,
                             const float* __restrict__ scaleshift)
{
    int i = blockIdx.x * blockDim.x + threadIdx.x;
    if (i >= M_CTR * COUT) return;
    int o = i & (COUT - 1);
    float a = scaleshift[o], b = scaleshift[COUT + o];
    float v = (a >= 0.f) ? y[i] : ymin[i];
    float z = fmaf(a, v, b);
    y[i] = fmaxf(z, 0.f);
}

extern "C" void kernel_launch(void* const* d_in, const int* in_sizes, int n_in,
                              void* d_out, int out_size, void* d_ws, size_t ws_size,
                              hipStream_t stream)
{
    const float* p     = (const float*)d_in[0];
    const float* nrm   = (const float*)d_in[1];
    const float* xf    = (const float*)d_in[2];
    // d_in[3] = o (unused: single batch, static sizes)
    const float* W     = (const float*)d_in[4];
    const float* gamma = (const float*)d_in[5];
    const float* beta  = (const float*)d_in[6];

    float* out = (float*)d_out;
    char* ws = (char*)d_ws;
    int*   sel        = (int*)(ws + 0);            // 16 KB
    float* pp2        = (float*)(ws + 16384);      // 64 KB
    int*   knn        = (int*)(ws + 81920);        // 256 KB (overlaid by spT during FPS)
    float* ymin       = (float*)(ws + 344064);     // 2 MB  (head overlaid by FPS scratch)
    float* partials   = (float*)(ws + 2441216);    // 1 MB
    float* scaleshift = (float*)(ws + 3489792);    // 1 KB

    // FPS scratch overlays (consumed before their hosts are written):
    float4*   spT       = (float4*)(ws + 81920);            // 256 KB in knn region
    char*     yb        = ws + 344064;                      // ymin region
    int*      c_of      = (int*)(yb + 65536);               // 64 KB
    int*      cellcnt   = (int*)(yb + 131072);              // 16 KB
    int*      cellfill  = (int*)(yb + 147456);              // 16 KB
    int*      cellstart = (int*)(yb + 163840);              // 16 KB
    float*    gbb       = (float*)(yb + 180224);            // 24 B

    float* ymax = out + 24576;  // y region of d_out

    init_kernel   <<<16, 256, 0, stream>>>(cellcnt, cellfill);
    bbox_kernel   <<<1,  256, 0, stream>>>(p, gbb);
    assign_kernel <<<64, 256, 0, stream>>>(p, gbb, c_of, cellcnt);
    prefix_kernel <<<1,  1024, 0, stream>>>(cellcnt, cellstart);
    scatter_kernel<<<64, 256, 0, stream>>>(p, c_of, cellstart, cellfill, spT);
    fps_kernel    <<<1,  NTH, 0, stream>>>(p, spT, sel);
    prep_kernel   <<<64, 256, 0, stream>>>(p, nrm, sel, pp2, out);
    knn_kernel    <<<1024, 256, 0, stream>>>(p, pp2, out, knn);
    passA_kernel  <<<M_CTR/CPB, 128, 0, stream>>>(p, xf, W, knn, out, ymax, ymin, partials);
    bnstat_kernel <<<1, 256, 0, stream>>>(partials, gamma, beta, scaleshift);
    final_kernel  <<<2048, 256, 0, stream>>>(ymax, ymin, scaleshift);
}

// Round 15
// 8458.607 us; speedup vs baseline: 2.0240x; 2.0240x over previous
//
#include <hip/hip_runtime.h>
#include <math.h>

#define N_PTS 16384
#define M_CTR 4096
#define NS 16
#define CIN 64
#define COUT 128
#define CFEAT 67
#define CPB 4          // centers per block in passA
#define NCELL 512      // 8x8x8 grid

typedef unsigned long long u64;

// order-preserving float<->uint transform (for atomic min/max on floats)
__device__ __forceinline__ unsigned ordu(float f) {
    unsigned b = __float_as_uint(f);
    return (b & 0x80000000u) ? ~b : (b | 0x80000000u);
}
__device__ __forceinline__ float unord(unsigned u) {
    unsigned b = (u & 0x80000000u) ? (u & 0x7FFFFFFFu) : ~u;
    return __uint_as_float(b);
}

// sorted-pair merge: (a1>=a2) U (b1>=b2) -> exact top-2 in (a1,a2)
__device__ __forceinline__ void pmerge(u64& a1, u64& a2, u64 b1, u64 b2) {
    u64 n1 = a1 > b1 ? a1 : b1;
    u64 lo = a1 > b1 ? b1 : a1;
    u64 m2 = a2 > b2 ? a2 : b2;
    a2 = lo > m2 ? lo : m2;
    a1 = n1;
}

// top-2 u64 merge via DPP (old=0 = identity for max)
#define DPP_TOP2(CTRL) do { \
    unsigned _o1lo = (unsigned)__builtin_amdgcn_update_dpp(0, (int)(unsigned)k1, CTRL, 0xF, 0xF, false); \
    unsigned _o1hi = (unsigned)__builtin_amdgcn_update_dpp(0, (int)(unsigned)(k1>>32), CTRL, 0xF, 0xF, false); \
    unsigned _o2lo = (unsigned)__builtin_amdgcn_update_dpp(0, (int)(unsigned)k2, CTRL, 0xF, 0xF, false); \
    unsigned _o2hi = (unsigned)__builtin_amdgcn_update_dpp(0, (int)(unsigned)(k2>>32), CTRL, 0xF, 0xF, false); \
    u64 _b1 = ((u64)_o1hi << 32) | (u64)_o1lo; \
    u64 _b2 = ((u64)_o2hi << 32) | (u64)_o2lo; \
    pmerge(k1, k2, _b1, _b2); \
} while (0)

// full-wave sweep (result at lane 63)
#define DPP_SWEEP64 DPP_TOP2(0x111); DPP_TOP2(0x112); DPP_TOP2(0x114); \
                    DPP_TOP2(0x118); DPP_TOP2(0x142); DPP_TOP2(0x143)
// segmented 32-lane sweep (results at lanes 31 and 63; no step crosses lane31)
#define DPP_SWEEP32 DPP_TOP2(0x111); DPP_TOP2(0x112); DPP_TOP2(0x114); \
                    DPP_TOP2(0x118); DPP_TOP2(0x142)

// ---------------- init: counters, bbox atoms ----------------
__global__ void init_kernel(unsigned* __restrict__ bmin, unsigned* __restrict__ bmax,
                            int* __restrict__ cnt, int* __restrict__ fill)
{
    int i = blockIdx.x * blockDim.x + threadIdx.x;
    if (i < NCELL * 3) { bmin[i] = 0xFFFFFFFFu; bmax[i] = 0u; }
    if (i < NCELL) { cnt[i] = 0; fill[i] = 0; }
}

// ---------------- cloud bbox (single block, deterministic) ----------------
__global__ __launch_bounds__(256) void bbox_kernel(const float* __restrict__ p,
                                                   float* __restrict__ gbb)
{
    int t = threadIdx.x, lane = t & 63, w = t >> 6;
    float mnx = 1e30f, mny = 1e30f, mnz = 1e30f;
    float mxx = -1e30f, mxy = -1e30f, mxz = -1e30f;
    for (int i = t; i < N_PTS; i += 256) {
        float x = p[i*3], y = p[i*3+1], z = p[i*3+2];
        mnx = fminf(mnx, x); mny = fminf(mny, y); mnz = fminf(mnz, z);
        mxx = fmaxf(mxx, x); mxy = fmaxf(mxy, y); mxz = fmaxf(mxz, z);
    }
    for (int m = 1; m < 64; m <<= 1) {
        mnx = fminf(mnx, __shfl_xor(mnx, m)); mny = fminf(mny, __shfl_xor(mny, m));
        mnz = fminf(mnz, __shfl_xor(mnz, m));
        mxx = fmaxf(mxx, __shfl_xor(mxx, m)); mxy = fmaxf(mxy, __shfl_xor(mxy, m));
        mxz = fmaxf(mxz, __shfl_xor(mxz, m));
    }
    __shared__ float s[4][6];
    if (lane == 0) { s[w][0]=mnx; s[w][1]=mny; s[w][2]=mnz; s[w][3]=mxx; s[w][4]=mxy; s[w][5]=mxz; }
    __syncthreads();
    if (t == 0) {
        gbb[0] = fminf(fminf(s[0][0], s[1][0]), fminf(s[2][0], s[3][0]));
        gbb[1] = fminf(fminf(s[0][1], s[1][1]), fminf(s[2][1], s[3][1]));
        gbb[2] = fminf(fminf(s[0][2], s[1][2]), fminf(s[2][2], s[3][2]));
        gbb[3] = fmaxf(fmaxf(s[0][3], s[1][3]), fmaxf(s[2][3], s[3][3]));
        gbb[4] = fmaxf(fmaxf(s[0][4], s[1][4]), fmaxf(s[2][4], s[3][4]));
        gbb[5] = fmaxf(fmaxf(s[0][5], s[1][5]), fmaxf(s[2][5], s[3][5]));
    }
}

// ---------------- assign points to cells ----------------
__global__ void assign_kernel(const float* __restrict__ p, const float* __restrict__ gbb,
                              int* __restrict__ c_of, int* __restrict__ cnt)
{
    int i = blockIdx.x * blockDim.x + threadIdx.x;
    if (i >= N_PTS) return;
    float bx = gbb[0], by = gbb[1], bz = gbb[2];
    float sx = 7.9999f / fmaxf(gbb[3] - bx, 1e-20f);
    float sy = 7.9999f / fmaxf(gbb[4] - by, 1e-20f);
    float sz = 7.9999f / fmaxf(gbb[5] - bz, 1e-20f);
    float x = p[i*3], y = p[i*3+1], z = p[i*3+2];
    int ix = min(7, max(0, (int)((x - bx) * sx)));
    int iy = min(7, max(0, (int)((y - by) * sy)));
    int iz = min(7, max(0, (int)((z - bz) * sz)));
    int c = (ix << 6) | (iy << 3) | iz;
    c_of[i] = c;
    atomicAdd(&cnt[c], 1);
}

// ---------------- exclusive prefix over 512 counts + packed meta ----------------
__global__ __launch_bounds__(512) void prefix_kernel(const int* __restrict__ cnt,
                                                     int* __restrict__ start,
                                                     int* __restrict__ cmeta)
{
    __shared__ int a[NCELL];
    int t = threadIdx.x;
    int v = cnt[t]; a[t] = v; __syncthreads();
    for (int off = 1; off < NCELL; off <<= 1) {
        int u = (t >= off) ? a[t - off] : 0;
        __syncthreads();
        a[t] += u;
        __syncthreads();
    }
    int st = a[t] - v;
    start[t] = st;
    cmeta[t] = (st << 15) | v;
}

// ---------------- scatter into sorted order + per-cell tight bbox ----------------
__global__ void scatter_kernel(const float* __restrict__ p, const int* __restrict__ c_of,
                               const int* __restrict__ start, int* __restrict__ fill,
                               float4* __restrict__ sp, unsigned* __restrict__ bmin,
                               unsigned* __restrict__ bmax)
{
    int i = blockIdx.x * blockDim.x + threadIdx.x;
    if (i >= N_PTS) return;
    int c = c_of[i];
    int pos = start[c] + atomicAdd(&fill[c], 1);
    float x = p[i*3], y = p[i*3+1], z = p[i*3+2];
    sp[pos] = make_float4(x, y, z, __int_as_float(i));
    atomicMin(&bmin[c*3+0], ordu(x)); atomicMax(&bmax[c*3+0], ordu(x));
    atomicMin(&bmin[c*3+1], ordu(y)); atomicMax(&bmax[c*3+1], ordu(y));
    atomicMin(&bmin[c*3+2], ordu(z)); atomicMax(&bmax[c*3+2], ordu(z));
}

// ---------------- FPS: r11 structure + 2-cells-per-wave segmented phase 2 ----------------
__global__ __launch_bounds__(1024) void fps_kernel(const float* __restrict__ p,
                                                   const float4* __restrict__ sp,
                                                   const int* __restrict__ g_cmeta,
                                                   const unsigned* __restrict__ g_bmin,
                                                   const unsigned* __restrict__ g_bmax,
                                                   int* __restrict__ sel)
{
    __shared__ float distl[N_PTS];                // 64 KB
    __shared__ u64 key1[NCELL], key2[NCELL];      // 8 KB exact per-cell top-2 (persistent)
    __shared__ int cmeta_s[NCELL];                // 2 KB
    __shared__ unsigned short wl[NCELL];          // 1 KB active cells
    __shared__ float bq[6];
    __shared__ int bnsel;
    __shared__ int wlc;

    const int t = threadIdx.x;
    const int lane = t & 63, wave = t >> 6;

    for (int i = t; i < N_PTS; i += 1024) distl[i] = 1e10f;

    int my_cnt = 0;
    float mnx=0.f, mny=0.f, mnz=0.f, mxx=0.f, mxy=0.f, mxz=0.f;
    if (t < NCELL) {
        int meta = g_cmeta[t];
        cmeta_s[t] = meta;
        my_cnt = meta & 0x7FFF;
        mnx = unord(g_bmin[t*3+0]); mny = unord(g_bmin[t*3+1]); mnz = unord(g_bmin[t*3+2]);
        mxx = unord(g_bmax[t*3+0]); mxy = unord(g_bmax[t*3+1]); mxz = unord(g_bmax[t*3+2]);
        key1[t] = 0ull; key2[t] = 0ull;
    }
    if (t == 0) { wlc = 0; sel[0] = 0; }
    float q1x = p[0], q1y = p[1], q1z = p[2];
    float q2x = 0.f, q2y = 0.f, q2z = 0.f;
    bool two = false;
    bool first = true;
    __syncthreads();

    int it = 1;
    while (it < M_CTR) {
        // ---- phase 1: prune (f32, registers + one LDS key read) + ballot append
        bool act = false;
        if (my_cnt > 0) {
            if (first) act = true;
            else {
                float cm = __uint_as_float((unsigned)(key1[t] >> 32)) * 1.00001f;
                float ddx = fmaxf(fmaxf(__fsub_rn(mnx, q1x), __fsub_rn(q1x, mxx)), 0.f);
                float ddy = fmaxf(fmaxf(__fsub_rn(mny, q1y), __fsub_rn(q1y, mxy)), 0.f);
                float ddz = fmaxf(fmaxf(__fsub_rn(mnz, q1z), __fsub_rn(q1z, mxz)), 0.f);
                float dm1 = __fadd_rn(__fadd_rn(__fmul_rn(ddx,ddx), __fmul_rn(ddy,ddy)),
                                      __fmul_rn(ddz,ddz));
                act = dm1 < cm;
                if (!act && two) {
                    float ex = fmaxf(fmaxf(__fsub_rn(mnx, q2x), __fsub_rn(q2x, mxx)), 0.f);
                    float ey = fmaxf(fmaxf(__fsub_rn(mny, q2y), __fsub_rn(q2y, mxy)), 0.f);
                    float ez = fmaxf(fmaxf(__fsub_rn(mnz, q2z), __fsub_rn(q2z, mxz)), 0.f);
                    float dm2 = __fadd_rn(__fadd_rn(__fmul_rn(ex,ex), __fmul_rn(ey,ey)),
                                          __fmul_rn(ez,ez));
                    act = dm2 < cm;
                }
            }
        }
        unsigned long long mask = __ballot(act);
        int base = 0;
        if (lane == 0 && mask) base = atomicAdd(&wlc, (int)__popcll(mask));
        base = __shfl(base, 0);
        if (act)
            wl[base + (int)__popcll(mask & ((1ull << lane) - 1ull))] = (unsigned short)t;
        __syncthreads();
        const int nwl = wlc;

        // ---- phase 2: TWO cells per wave (lanes 0-31 / 32-63), segmented sweep
        for (int e0 = (wave << 1); e0 < nwl; e0 += 32) {
            int cA = wl[e0];
            int cB = (e0 + 1 < nwl) ? (int)wl[e0 + 1] : -1;
            int c = (lane >> 5) ? cB : cA;
            u64 k1 = 0ull, k2 = 0ull;
            if (c >= 0) {
                int mv = cmeta_s[c];
                int st = mv >> 15, cnt = mv & 0x7FFF;
                for (int o = (lane & 31); o < cnt; o += 32) {
                    int g = st + o;
                    float4 P = sp[g];
                    float D = distl[g];
                    float dx = __fsub_rn(P.x, q1x), dy = __fsub_rn(P.y, q1y), dz = __fsub_rn(P.z, q1z);
                    float d2 = __fadd_rn(__fadd_rn(__fmul_rn(dx,dx), __fmul_rn(dy,dy)),
                                         __fmul_rn(dz,dz));
                    float nd = fminf(D, d2);
                    if (two) {
                        float ex = __fsub_rn(P.x, q2x), ey = __fsub_rn(P.y, q2y), ez = __fsub_rn(P.z, q2z);
                        float e2 = __fadd_rn(__fadd_rn(__fmul_rn(ex,ex), __fmul_rn(ey,ey)),
                                             __fmul_rn(ez,ez));
                        nd = fminf(nd, e2);
                    }
                    distl[g] = nd;
                    u64 kk = ((u64)__float_as_uint(nd) << 32)
                           | (u64)(~(unsigned)__float_as_int(P.w));
                    if (kk > k1) { k2 = k1; k1 = kk; }
                    else if (kk > k2) { k2 = kk; }
                }
            }
            DPP_SWEEP32;                 // lanes 31/63 = exact per-half top-2
            if ((lane & 31) == 31 && c >= 0) { key1[c] = k1; key2[c] = k2; }
        }
        if (t == 1023) wlc = 0;   // safe: wlc unused until next round's append
        __syncthreads();

        // ---- phase 3: wave 0 only — global top-2, accept test, q fetch, broadcast
        if (wave == 0) {
            u64 k1 = 0ull, k2 = 0ull;
#pragma unroll
            for (int j = 0; j < 8; ++j) {
                int c = lane + (j << 6);
                pmerge(k1, k2, key1[c], key2[c]);
            }
            DPP_SWEEP64;
            if (lane == 63) {
                u64 A1 = k1, A2 = k2;
                int s1 = (int)(~(unsigned)(A1 & 0xFFFFFFFFull));
                int s2 = (int)(~(unsigned)(A2 & 0xFFFFFFFFull));
                sel[it] = s1;
                float nq1x = p[s1*3+0], nq1y = p[s1*3+1], nq1z = p[s1*3+2];
                float bx2 = p[s2*3+0], by2 = p[s2*3+1], bz2 = p[s2*3+2];
                int nsel = 1;
                if (A2 != 0ull && it + 1 < M_CTR) {
                    // exact: if s1's update leaves the global #2 key unchanged,
                    // every other key can only drop below it -> s2 is next pick.
                    float dx = __fsub_rn(bx2, nq1x), dy = __fsub_rn(by2, nq1y), dz = __fsub_rn(bz2, nq1z);
                    float d2b = __fadd_rn(__fadd_rn(__fmul_rn(dx,dx), __fmul_rn(dy,dy)),
                                          __fmul_rn(dz,dz));
                    float db = __uint_as_float((unsigned)(A2 >> 32));
                    if (d2b >= db) { nsel = 2; sel[it + 1] = s2; }
                }
                bq[0] = nq1x; bq[1] = nq1y; bq[2] = nq1z;
                bq[3] = bx2;  bq[4] = by2;  bq[5] = bz2;
                bnsel = nsel;
            }
        }
        __syncthreads();
        int nsel = bnsel;
        q1x = bq[0]; q1y = bq[1]; q1z = bq[2];
        two = (nsel == 2);
        if (two) { q2x = bq[3]; q2y = bq[4]; q2z = bq[5]; }
        first = false;
        it += nsel;
    }
}

// ---------------- prep: pp2, gather n_p/n_n, write n_o ----------------
__global__ void prep_kernel(const float* __restrict__ p, const float* __restrict__ nrm,
                            const int* __restrict__ sel, float* __restrict__ pp2,
                            float* __restrict__ out)
{
    int i = blockIdx.x * blockDim.x + threadIdx.x;
    if (i < N_PTS) {
        float x = p[i*3], y = p[i*3+1], z = p[i*3+2];
        pp2[i] = __fadd_rn(__fadd_rn(__fmul_rn(x,x), __fmul_rn(y,y)), __fmul_rn(z,z));
    }
    if (i < M_CTR) {
        int j = sel[i];
        out[i*3+0] = p[j*3+0]; out[i*3+1] = p[j*3+1]; out[i*3+2] = p[j*3+2];
        out[12288 + i*3+0] = nrm[j*3+0];
        out[12288 + i*3+1] = nrm[j*3+1];
        out[12288 + i*3+2] = nrm[j*3+2];
    }
    if (i == 0) out[548864] = (float)M_CTR;   // n_o
}

// ---------------- kNN: one wave per center, per-lane sorted top-16 ----------------
__global__ __launch_bounds__(256) void knn_kernel(const float* __restrict__ p,
                                                  const float* __restrict__ pp2,
                                                  const float* __restrict__ np /* n_p */,
                                                  int* __restrict__ knn)
{
    const int lane = threadIdx.x & 63;
    const int wave = threadIdx.x >> 6;
    const int c = blockIdx.x * 4 + wave;

    float cx = np[c*3], cy = np[c*3+1], cz = np[c*3+2];
    float c2 = __fadd_rn(__fadd_rn(__fmul_rn(cx,cx), __fmul_rn(cy,cy)), __fmul_rn(cz,cz));

    float hd[16]; int hi[16];
#pragma unroll
    for (int k = 0; k < 16; ++k) { hd[k] = 1e30f; hi[k] = 0x7fffffff; }

    for (int t = 0; t < N_PTS/64; ++t) {
        int j = t*64 + lane;
        float px = p[j*3+0], py = p[j*3+1], pz = p[j*3+2];
        float dot = __fadd_rn(__fadd_rn(__fmul_rn(cx,px), __fmul_rn(cy,py)),
                              __fmul_rn(cz,pz));
        float d2  = __fsub_rn(__fadd_rn(c2, pp2[j]), __fmul_rn(2.0f, dot));
        if (d2 < hd[15]) {
#pragma unroll
            for (int k = 15; k >= 1; --k) {
                bool up   = d2 < hd[k-1];
                bool here = d2 < hd[k];
                hd[k] = up ? hd[k-1] : (here ? d2 : hd[k]);
                hi[k] = up ? hi[k-1] : (here ? j  : hi[k]);
            }
            if (d2 < hd[0]) { hd[0] = d2; hi[0] = j; }
        }
    }

    for (int r = 0; r < 16; ++r) {
        float wv = hd[0]; int wi = hi[0];
#pragma unroll
        for (int m = 1; m < 64; m <<= 1) {
            float ov = __shfl_xor(wv, m);
            int   oi = __shfl_xor(wi, m);
            bool b = (ov < wv) || (ov == wv && oi < wi);
            wv = b ? ov : wv; wi = b ? oi : wi;
        }
        if (hi[0] == wi) {
            knn[c*16 + r] = wi;
#pragma unroll
            for (int k = 0; k < 15; ++k) { hd[k] = hd[k+1]; hi[k] = hi[k+1]; }
            hd[15] = 1e30f; hi[15] = 0x7fffffff;
        }
    }
}

// ---------------- pass A: feat build + GEMM + stats + ymax/ymin ----------------
__global__ __launch_bounds__(128) void passA_kernel(const float* __restrict__ p,
                                                    const float* __restrict__ xf,
                                                    const float* __restrict__ W,
                                                    const int* __restrict__ knn,
                                                    const float* __restrict__ out /* n_p */,
                                                    float* __restrict__ ymax,
                                                    float* __restrict__ ymin,
                                                    float* __restrict__ partials)
{
    __shared__ float Wt[CFEAT][COUT];
    __shared__ float ft[CPB][NS][CFEAT];
    __shared__ float bsum[CPB][COUT], bssq[CPB][COUT];

    const int t = threadIdx.x;
    const int mbase = blockIdx.x * CPB;

    for (int c = 0; c < CFEAT; ++c) Wt[c][t] = W[t*CFEAT + c];

    {
        int r = t >> 1, half = t & 1;
        int ci = r >> 4, s = r & 15;
        int m = mbase + ci;
        int nb = knn[m*NS + s];
        if (half == 0) {
            ft[ci][s][0] = __fsub_rn(p[nb*3+0], out[m*3+0]);
            ft[ci][s][1] = __fsub_rn(p[nb*3+1], out[m*3+1]);
            ft[ci][s][2] = __fsub_rn(p[nb*3+2], out[m*3+2]);
        }
        for (int c = half*32; c < half*32 + 32; ++c)
            ft[ci][s][3+c] = xf[nb*CIN + c];
    }
    __syncthreads();

    const int ci = t >> 5, l = t & 31;
    float acc[NS][4];
#pragma unroll
    for (int s = 0; s < NS; ++s) { acc[s][0]=0.f; acc[s][1]=0.f; acc[s][2]=0.f; acc[s][3]=0.f; }

    for (int c = 0; c < CFEAT; ++c) {
        float w0 = Wt[c][l], w1 = Wt[c][l+32], w2 = Wt[c][l+64], w3 = Wt[c][l+96];
#pragma unroll
        for (int s = 0; s < NS; ++s) {
            float f = ft[ci][s][c];
            acc[s][0] = fmaf(f, w0, acc[s][0]);
            acc[s][1] = fmaf(f, w1, acc[s][1]);
            acc[s][2] = fmaf(f, w2, acc[s][2]);
            acc[s][3] = fmaf(f, w3, acc[s][3]);
        }
    }

    const int m = mbase + ci;
#pragma unroll
    for (int j = 0; j < 4; ++j) {
        int o = l + 32*j;
        float s = 0.f, q = 0.f, mx = -1e30f, mn = 1e30f;
#pragma unroll
        for (int sidx = 0; sidx < NS; ++sidx) {
            float v = acc[sidx][j];
            s += v; q = fmaf(v, v, q);
            mx = fmaxf(mx, v); mn = fminf(mn, v);
        }
        bsum[ci][o] = s;
        bssq[ci][o] = q;
        ymax[m*COUT + o] = mx;
        ymin[m*COUT + o] = mn;
    }
    __syncthreads();
    if (t < COUT) {
        float s = bsum[0][t] + bsum[1][t] + bsum[2][t] + bsum[3][t];
        float q = bssq[0][t] + bssq[1][t] + bssq[2][t] + bssq[3][t];
        partials[t*1024          + blockIdx.x] = s;
        partials[(COUT + t)*1024 + blockIdx.x] = q;
    }
}

// ---------------- BN stats reduce -> scale/shift ----------------
__global__ __launch_bounds__(256) void bnstat_kernel(const float* __restrict__ partials,
                                                     const float* __restrict__ gamma,
                                                     const float* __restrict__ beta,
                                                     float* __restrict__ scaleshift)
{
    __shared__ float red[256];
    int t = threadIdx.x;
    const float4* v4 = (const float4*)(partials + t*1024);
    float s = 0.f;
    for (int i = 0; i < 256; ++i) {
        float4 v = v4[i];
        s += v.x; s += v.y; s += v.z; s += v.w;
    }
    red[t] = s;
    __syncthreads();
    if (t < COUT) {
        const float inv = 1.0f / 65536.0f;
        float mean = red[t] * inv;
        float var  = red[COUT + t] * inv - mean*mean;
        float rstd = rsqrtf(var + 1e-5f);
        float g = gamma[t] * rstd;
        scaleshift[t]        = g;
        scaleshift[COUT + t] = beta[t] - mean * g;
    }
}

// ---------------- final: BN apply + ReLU on the pooled extreme ----------------
__global__ void final_kernel(float* __restrict__ y,
                             const float* __restrict__ ymin,
                             const float* __restrict__ scaleshift)
{
    int i = blockIdx.x * blockDim.x + threadIdx.x;
    if (i >= M_CTR * COUT) return;
    int o = i & (COUT - 1);
    float a = scaleshift[o], b = scaleshift[COUT + o];
    float v = (a >= 0.f) ? y[i] : ymin[i];
    float z = fmaf(a, v, b);
    y[i] = fmaxf(z, 0.f);
}

extern "C" void kernel_launch(void* const* d_in, const int* in_sizes, int n_in,
                              void* d_out, int out_size, void* d_ws, size_t ws_size,
                              hipStream_t stream)
{
    const float* p     = (const float*)d_in[0];
    const float* nrm   = (const float*)d_in[1];
    const float* xf    = (const float*)d_in[2];
    // d_in[3] = o (unused: single batch, static sizes)
    const float* W     = (const float*)d_in[4];
    const float* gamma = (const float*)d_in[5];
    const float* beta  = (const float*)d_in[6];

    float* out = (float*)d_out;
    char* ws = (char*)d_ws;
    int*   sel        = (int*)(ws + 0);            // 16 KB
    float* pp2        = (float*)(ws + 16384);      // 64 KB
    int*   knn        = (int*)(ws + 81920);        // 256 KB (overlaid by sp during FPS)
    float* ymin       = (float*)(ws + 344064);     // 2 MB  (head overlaid by FPS scratch)
    float* partials   = (float*)(ws + 2441216);    // 1 MB
    float* scaleshift = (float*)(ws + 3489792);    // 1 KB

    // FPS scratch overlays (consumed before their hosts are written):
    float4*   sp        = (float4*)(ws + 81920);            // 256 KB in knn region
    char*     yb        = ws + 344064;                      // ymin region
    int*      c_of      = (int*)(yb + 65536);               // 64 KB
    int*      cellcnt   = (int*)(yb + 131072);              // 2 KB
    int*      cellfill  = (int*)(yb + 133120);              // 2 KB
    int*      cellstart = (int*)(yb + 135168);              // 2 KB
    unsigned* bbmin_u   = (unsigned*)(yb + 137216);         // 6 KB
    unsigned* bbmax_u   = (unsigned*)(yb + 143360);         // 6 KB
    float*    gbb       = (float*)(yb + 149504);            // 24 B
    int*      cmeta_g   = (int*)(yb + 149536);              // 2 KB

    float* ymax = out + 24576;  // y region of d_out

    init_kernel   <<<8,  256, 0, stream>>>(bbmin_u, bbmax_u, cellcnt, cellfill);
    bbox_kernel   <<<1,  256, 0, stream>>>(p, gbb);
    assign_kernel <<<64, 256, 0, stream>>>(p, gbb, c_of, cellcnt);
    prefix_kernel <<<1,  512, 0, stream>>>(cellcnt, cellstart, cmeta_g);
    scatter_kernel<<<64, 256, 0, stream>>>(p, c_of, cellstart, cellfill, sp, bbmin_u, bbmax_u);
    fps_kernel    <<<1,  1024, 0, stream>>>(p, sp, cmeta_g, bbmin_u, bbmax_u, sel);
    prep_kernel   <<<64, 256, 0, stream>>>(p, nrm, sel, pp2, out);
    knn_kernel    <<<1024, 256, 0, stream>>>(p, pp2, out, knn);
    passA_kernel  <<<M_CTR/CPB, 128, 0, stream>>>(p, xf, W, knn, out, ymax, ymin, partials);
    bnstat_kernel <<<1, 256, 0, stream>>>(partials, gamma, beta, scaleshift);
    final_kernel  <<<2048, 256, 0, stream>>>(ymax, ymin, scaleshift);
}

// Round 16
// 6956.874 us; speedup vs baseline: 2.4610x; 1.2159x over previous
//
#include <hip/hip_runtime.h>
#include <math.h>

#define N_PTS 16384
#define M_CTR 4096
#define NS 16
#define CIN 64
#define COUT 128
#define CFEAT 67
#define CPB 4          // centers per block in passA
#define NCELL 512      // 8x8x8 grid

typedef unsigned long long u64;

// order-preserving float<->uint transform (for atomic min/max on floats)
__device__ __forceinline__ unsigned ordu(float f) {
    unsigned b = __float_as_uint(f);
    return (b & 0x80000000u) ? ~b : (b | 0x80000000u);
}
__device__ __forceinline__ float unord(unsigned u) {
    unsigned b = (u & 0x80000000u) ? (u & 0x7FFFFFFFu) : ~u;
    return __uint_as_float(b);
}

// sorted-pair merge: (a1>=a2) U (b1>=b2) -> exact top-2 in (a1,a2)
__device__ __forceinline__ void pmerge(u64& a1, u64& a2, u64 b1, u64 b2) {
    u64 n1 = a1 > b1 ? a1 : b1;
    u64 lo = a1 > b1 ? b1 : a1;
    u64 m2 = a2 > b2 ? a2 : b2;
    a2 = lo > m2 ? lo : m2;
    a1 = n1;
}

// top-2 u64 merge via DPP (old=0 = identity for max)
#define DPP_TOP2(CTRL) do { \
    unsigned _o1lo = (unsigned)__builtin_amdgcn_update_dpp(0, (int)(unsigned)k1, CTRL, 0xF, 0xF, false); \
    unsigned _o1hi = (unsigned)__builtin_amdgcn_update_dpp(0, (int)(unsigned)(k1>>32), CTRL, 0xF, 0xF, false); \
    unsigned _o2lo = (unsigned)__builtin_amdgcn_update_dpp(0, (int)(unsigned)k2, CTRL, 0xF, 0xF, false); \
    unsigned _o2hi = (unsigned)__builtin_amdgcn_update_dpp(0, (int)(unsigned)(k2>>32), CTRL, 0xF, 0xF, false); \
    u64 _b1 = ((u64)_o1hi << 32) | (u64)_o1lo; \
    u64 _b2 = ((u64)_o2hi << 32) | (u64)_o2lo; \
    pmerge(k1, k2, _b1, _b2); \
} while (0)

#define DPP_SWEEP64 DPP_TOP2(0x111); DPP_TOP2(0x112); DPP_TOP2(0x114); \
                    DPP_TOP2(0x118); DPP_TOP2(0x142); DPP_TOP2(0x143)

// ---------------- init: counters, bbox atoms ----------------
__global__ void init_kernel(unsigned* __restrict__ bmin, unsigned* __restrict__ bmax,
                            int* __restrict__ cnt, int* __restrict__ fill)
{
    int i = blockIdx.x * blockDim.x + threadIdx.x;
    if (i < NCELL * 3) { bmin[i] = 0xFFFFFFFFu; bmax[i] = 0u; }
    if (i < NCELL) { cnt[i] = 0; fill[i] = 0; }
}

// ---------------- cloud bbox (single block, deterministic) ----------------
__global__ __launch_bounds__(256) void bbox_kernel(const float* __restrict__ p,
                                                   float* __restrict__ gbb)
{
    int t = threadIdx.x, lane = t & 63, w = t >> 6;
    float mnx = 1e30f, mny = 1e30f, mnz = 1e30f;
    float mxx = -1e30f, mxy = -1e30f, mxz = -1e30f;
    for (int i = t; i < N_PTS; i += 256) {
        float x = p[i*3], y = p[i*3+1], z = p[i*3+2];
        mnx = fminf(mnx, x); mny = fminf(mny, y); mnz = fminf(mnz, z);
        mxx = fmaxf(mxx, x); mxy = fmaxf(mxy, y); mxz = fmaxf(mxz, z);
    }
    for (int m = 1; m < 64; m <<= 1) {
        mnx = fminf(mnx, __shfl_xor(mnx, m)); mny = fminf(mny, __shfl_xor(mny, m));
        mnz = fminf(mnz, __shfl_xor(mnz, m));
        mxx = fmaxf(mxx, __shfl_xor(mxx, m)); mxy = fmaxf(mxy, __shfl_xor(mxy, m));
        mxz = fmaxf(mxz, __shfl_xor(mxz, m));
    }
    __shared__ float s[4][6];
    if (lane == 0) { s[w][0]=mnx; s[w][1]=mny; s[w][2]=mnz; s[w][3]=mxx; s[w][4]=mxy; s[w][5]=mxz; }
    __syncthreads();
    if (t == 0) {
        gbb[0] = fminf(fminf(s[0][0], s[1][0]), fminf(s[2][0], s[3][0]));
        gbb[1] = fminf(fminf(s[0][1], s[1][1]), fminf(s[2][1], s[3][1]));
        gbb[2] = fminf(fminf(s[0][2], s[1][2]), fminf(s[2][2], s[3][2]));
        gbb[3] = fmaxf(fmaxf(s[0][3], s[1][3]), fmaxf(s[2][3], s[3][3]));
        gbb[4] = fmaxf(fmaxf(s[0][4], s[1][4]), fmaxf(s[2][4], s[3][4]));
        gbb[5] = fmaxf(fmaxf(s[0][5], s[1][5]), fmaxf(s[2][5], s[3][5]));
    }
}

// ---------------- assign points to cells ----------------
__global__ void assign_kernel(const float* __restrict__ p, const float* __restrict__ gbb,
                              int* __restrict__ c_of, int* __restrict__ cnt)
{
    int i = blockIdx.x * blockDim.x + threadIdx.x;
    if (i >= N_PTS) return;
    float bx = gbb[0], by = gbb[1], bz = gbb[2];
    float sx = 7.9999f / fmaxf(gbb[3] - bx, 1e-20f);
    float sy = 7.9999f / fmaxf(gbb[4] - by, 1e-20f);
    float sz = 7.9999f / fmaxf(gbb[5] - bz, 1e-20f);
    float x = p[i*3], y = p[i*3+1], z = p[i*3+2];
    int ix = min(7, max(0, (int)((x - bx) * sx)));
    int iy = min(7, max(0, (int)((y - by) * sy)));
    int iz = min(7, max(0, (int)((z - bz) * sz)));
    int c = (ix << 6) | (iy << 3) | iz;
    c_of[i] = c;
    atomicAdd(&cnt[c], 1);
}

// ---------------- exclusive prefix over 512 counts + packed meta ----------------
__global__ __launch_bounds__(512) void prefix_kernel(const int* __restrict__ cnt,
                                                     int* __restrict__ start,
                                                     int* __restrict__ cmeta)
{
    __shared__ int a[NCELL];
    int t = threadIdx.x;
    int v = cnt[t]; a[t] = v; __syncthreads();
    for (int off = 1; off < NCELL; off <<= 1) {
        int u = (t >= off) ? a[t - off] : 0;
        __syncthreads();
        a[t] += u;
        __syncthreads();
    }
    int st = a[t] - v;
    start[t] = st;
    cmeta[t] = (st << 15) | v;
}

// ---------------- scatter into sorted order + per-cell tight bbox ----------------
__global__ void scatter_kernel(const float* __restrict__ p, const int* __restrict__ c_of,
                               const int* __restrict__ start, int* __restrict__ fill,
                               float4* __restrict__ sp, unsigned* __restrict__ bmin,
                               unsigned* __restrict__ bmax)
{
    int i = blockIdx.x * blockDim.x + threadIdx.x;
    if (i >= N_PTS) return;
    int c = c_of[i];
    int pos = start[c] + atomicAdd(&fill[c], 1);
    float x = p[i*3], y = p[i*3+1], z = p[i*3+2];
    sp[pos] = make_float4(x, y, z, __int_as_float(i));
    atomicMin(&bmin[c*3+0], ordu(x)); atomicMax(&bmax[c*3+0], ordu(x));
    atomicMin(&bmin[c*3+1], ordu(y)); atomicMax(&bmax[c*3+1], ordu(y));
    atomicMin(&bmin[c*3+2], ordu(z)); atomicMax(&bmax[c*3+2], ordu(z));
}

// ---------------- FPS: r11 structure + 4-way ILP per-cell scan ----------------
__global__ __launch_bounds__(1024) void fps_kernel(const float* __restrict__ p,
                                                   const float4* __restrict__ sp,
                                                   const int* __restrict__ g_cmeta,
                                                   const unsigned* __restrict__ g_bmin,
                                                   const unsigned* __restrict__ g_bmax,
                                                   int* __restrict__ sel)
{
    __shared__ float distl[N_PTS];                // 64 KB
    __shared__ u64 key1[NCELL], key2[NCELL];      // 8 KB exact per-cell top-2 (persistent)
    __shared__ int cmeta_s[NCELL];                // 2 KB
    __shared__ unsigned short wl[NCELL];          // 1 KB active cells
    __shared__ float bq[6];
    __shared__ int bnsel;
    __shared__ int wlc;

    const int t = threadIdx.x;
    const int lane = t & 63, wave = t >> 6;

    for (int i = t; i < N_PTS; i += 1024) distl[i] = 1e10f;

    int my_cnt = 0;
    float mnx=0.f, mny=0.f, mnz=0.f, mxx=0.f, mxy=0.f, mxz=0.f;
    if (t < NCELL) {
        int meta = g_cmeta[t];
        cmeta_s[t] = meta;
        my_cnt = meta & 0x7FFF;
        mnx = unord(g_bmin[t*3+0]); mny = unord(g_bmin[t*3+1]); mnz = unord(g_bmin[t*3+2]);
        mxx = unord(g_bmax[t*3+0]); mxy = unord(g_bmax[t*3+1]); mxz = unord(g_bmax[t*3+2]);
        key1[t] = 0ull; key2[t] = 0ull;
    }
    if (t == 0) { wlc = 0; sel[0] = 0; }
    float q1x = p[0], q1y = p[1], q1z = p[2];
    float q2x = 0.f, q2y = 0.f, q2z = 0.f;
    bool two = false;
    bool first = true;
    __syncthreads();

    int it = 1;
    while (it < M_CTR) {
        // ---- phase 1: prune (f32, registers + one LDS key read) + ballot append
        bool act = false;
        if (my_cnt > 0) {
            if (first) act = true;
            else {
                float cm = __uint_as_float((unsigned)(key1[t] >> 32)) * 1.00001f;
                float ddx = fmaxf(fmaxf(__fsub_rn(mnx, q1x), __fsub_rn(q1x, mxx)), 0.f);
                float ddy = fmaxf(fmaxf(__fsub_rn(mny, q1y), __fsub_rn(q1y, mxy)), 0.f);
                float ddz = fmaxf(fmaxf(__fsub_rn(mnz, q1z), __fsub_rn(q1z, mxz)), 0.f);
                float dm1 = __fadd_rn(__fadd_rn(__fmul_rn(ddx,ddx), __fmul_rn(ddy,ddy)),
                                      __fmul_rn(ddz,ddz));
                act = dm1 < cm;
                if (!act && two) {
                    float ex = fmaxf(fmaxf(__fsub_rn(mnx, q2x), __fsub_rn(q2x, mxx)), 0.f);
                    float ey = fmaxf(fmaxf(__fsub_rn(mny, q2y), __fsub_rn(q2y, mxy)), 0.f);
                    float ez = fmaxf(fmaxf(__fsub_rn(mnz, q2z), __fsub_rn(q2z, mxz)), 0.f);
                    float dm2 = __fadd_rn(__fadd_rn(__fmul_rn(ex,ex), __fmul_rn(ey,ey)),
                                          __fmul_rn(ez,ez));
                    act = dm2 < cm;
                }
            }
        }
        unsigned long long mask = __ballot(act);
        int base = 0;
        if (lane == 0 && mask) base = atomicAdd(&wlc, (int)__popcll(mask));
        base = __shfl(base, 0);
        if (act)
            wl[base + (int)__popcll(mask & ((1ull << lane) - 1ull))] = (unsigned short)t;
        __syncthreads();
        const int nwl = wlc;

        // ---- phase 2: one wave per active cell; 4-way ILP scan; exact top-2
        for (int e = wave; e < nwl; e += 16) {
            int c = wl[e];
            int mv = cmeta_s[c];
            int st = mv >> 15, cnt = mv & 0x7FFF;

            u64 a1 = 0ull, a2 = 0ull, b1 = 0ull, b2 = 0ull;
            u64 c1 = 0ull, c2 = 0ull, d1 = 0ull, d2_ = 0ull;

#define PROC(OFF, K1, K2) { \
            int g = st + (OFF); \
            float4 P = sp[g]; \
            float D = distl[g]; \
            float dx = __fsub_rn(P.x, q1x), dy = __fsub_rn(P.y, q1y), dz = __fsub_rn(P.z, q1z); \
            float d2v = __fadd_rn(__fadd_rn(__fmul_rn(dx,dx), __fmul_rn(dy,dy)), \
                                  __fmul_rn(dz,dz)); \
            float nd = fminf(D, d2v); \
            if (two) { \
                float ex = __fsub_rn(P.x, q2x), ey = __fsub_rn(P.y, q2y), ez = __fsub_rn(P.z, q2z); \
                float e2 = __fadd_rn(__fadd_rn(__fmul_rn(ex,ex), __fmul_rn(ey,ey)), \
                                     __fmul_rn(ez,ez)); \
                nd = fminf(nd, e2); \
            } \
            distl[g] = nd; \
            u64 kk = ((u64)__float_as_uint(nd) << 32) \
                   | (u64)(~(unsigned)__float_as_int(P.w)); \
            if (kk > K1) { K2 = K1; K1 = kk; } \
            else if (kk > K2) { K2 = kk; } }

            for (int o = lane; o < cnt; o += 256) {
                PROC(o, a1, a2)
                int o2 = o + 64;
                if (o2 < cnt) PROC(o2, b1, b2)
                int o3 = o + 128;
                if (o3 < cnt) PROC(o3, c1, c2)
                int o4 = o + 192;
                if (o4 < cnt) PROC(o4, d1, d2_)
            }
#undef PROC
            pmerge(a1, a2, b1, b2);
            pmerge(c1, c2, d1, d2_);
            pmerge(a1, a2, c1, c2);
            u64 k1 = a1, k2 = a2;
            DPP_SWEEP64;                 // lane63 = exact cell top-2
            if (lane == 63) { key1[c] = k1; key2[c] = k2; }
        }
        if (t == 1023) wlc = 0;   // safe: wlc unused until next round's append
        __syncthreads();

        // ---- phase 3: wave 0 only — global top-2, accept test, q fetch, broadcast
        if (wave == 0) {
            u64 k1 = 0ull, k2 = 0ull;
#pragma unroll
            for (int j = 0; j < 8; ++j) {
                int c = lane + (j << 6);
                pmerge(k1, k2, key1[c], key2[c]);
            }
            DPP_SWEEP64;
            if (lane == 63) {
                u64 A1 = k1, A2 = k2;
                int s1 = (int)(~(unsigned)(A1 & 0xFFFFFFFFull));
                int s2 = (int)(~(unsigned)(A2 & 0xFFFFFFFFull));
                sel[it] = s1;
                float nq1x = p[s1*3+0], nq1y = p[s1*3+1], nq1z = p[s1*3+2];
                float bx2 = p[s2*3+0], by2 = p[s2*3+1], bz2 = p[s2*3+2];
                int nsel = 1;
                if (A2 != 0ull && it + 1 < M_CTR) {
                    // exact: if s1's update leaves the global #2 key unchanged,
                    // every other key can only drop below it -> s2 is next pick.
                    float dx = __fsub_rn(bx2, nq1x), dy = __fsub_rn(by2, nq1y), dz = __fsub_rn(bz2, nq1z);
                    float d2b = __fadd_rn(__fadd_rn(__fmul_rn(dx,dx), __fmul_rn(dy,dy)),
                                          __fmul_rn(dz,dz));
                    float db = __uint_as_float((unsigned)(A2 >> 32));
                    if (d2b >= db) { nsel = 2; sel[it + 1] = s2; }
                }
                bq[0] = nq1x; bq[1] = nq1y; bq[2] = nq1z;
                bq[3] = bx2;  bq[4] = by2;  bq[5] = bz2;
                bnsel = nsel;
            }
        }
        __syncthreads();
        int nsel = bnsel;
        q1x = bq[0]; q1y = bq[1]; q1z = bq[2];
        two = (nsel == 2);
        if (two) { q2x = bq[3]; q2y = bq[4]; q2z = bq[5]; }
        first = false;
        it += nsel;
    }
}

// ---------------- prep: pp2, gather n_p/n_n, write n_o ----------------
__global__ void prep_kernel(const float* __restrict__ p, const float* __restrict__ nrm,
                            const int* __restrict__ sel, float* __restrict__ pp2,
                            float* __restrict__ out)
{
    int i = blockIdx.x * blockDim.x + threadIdx.x;
    if (i < N_PTS) {
        float x = p[i*3], y = p[i*3+1], z = p[i*3+2];
        pp2[i] = __fadd_rn(__fadd_rn(__fmul_rn(x,x), __fmul_rn(y,y)), __fmul_rn(z,z));
    }
    if (i < M_CTR) {
        int j = sel[i];
        out[i*3+0] = p[j*3+0]; out[i*3+1] = p[j*3+1]; out[i*3+2] = p[j*3+2];
        out[12288 + i*3+0] = nrm[j*3+0];
        out[12288 + i*3+1] = nrm[j*3+1];
        out[12288 + i*3+2] = nrm[j*3+2];
    }
    if (i == 0) out[548864] = (float)M_CTR;   // n_o
}

// ---------------- kNN: one wave per center, per-lane sorted top-16 ----------------
__global__ __launch_bounds__(256) void knn_kernel(const float* __restrict__ p,
                                                  const float* __restrict__ pp2,
                                                  const float* __restrict__ np /* n_p */,
                                                  int* __restrict__ knn)
{
    const int lane = threadIdx.x & 63;
    const int wave = threadIdx.x >> 6;
    const int c = blockIdx.x * 4 + wave;

    float cx = np[c*3], cy = np[c*3+1], cz = np[c*3+2];
    float c2 = __fadd_rn(__fadd_rn(__fmul_rn(cx,cx), __fmul_rn(cy,cy)), __fmul_rn(cz,cz));

    float hd[16]; int hi[16];
#pragma unroll
    for (int k = 0; k < 16; ++k) { hd[k] = 1e30f; hi[k] = 0x7fffffff; }

    for (int t = 0; t < N_PTS/64; ++t) {
        int j = t*64 + lane;
        float px = p[j*3+0], py = p[j*3+1], pz = p[j*3+2];
        float dot = __fadd_rn(__fadd_rn(__fmul_rn(cx,px), __fmul_rn(cy,py)),
                              __fmul_rn(cz,pz));
        float d2  = __fsub_rn(__fadd_rn(c2, pp2[j]), __fmul_rn(2.0f, dot));
        if (d2 < hd[15]) {
#pragma unroll
            for (int k = 15; k >= 1; --k) {
                bool up   = d2 < hd[k-1];
                bool here = d2 < hd[k];
                hd[k] = up ? hd[k-1] : (here ? d2 : hd[k]);
                hi[k] = up ? hi[k-1] : (here ? j  : hi[k]);
            }
            if (d2 < hd[0]) { hd[0] = d2; hi[0] = j; }
        }
    }

    for (int r = 0; r < 16; ++r) {
        float wv = hd[0]; int wi = hi[0];
#pragma unroll
        for (int m = 1; m < 64; m <<= 1) {
            float ov = __shfl_xor(wv, m);
            int   oi = __shfl_xor(wi, m);
            bool b = (ov < wv) || (ov == wv && oi < wi);
            wv = b ? ov : wv; wi = b ? oi : wi;
        }
        if (hi[0] == wi) {
            knn[c*16 + r] = wi;
#pragma unroll
            for (int k = 0; k < 15; ++k) { hd[k] = hd[k+1]; hi[k] = hi[k+1]; }
            hd[15] = 1e30f; hi[15] = 0x7fffffff;
        }
    }
}

// ---------------- pass A: feat build + GEMM + stats + ymax/ymin ----------------
__global__ __launch_bounds__(128) void passA_kernel(const float* __restrict__ p,
                                                    const float* __restrict__ xf,
                                                    const float* __restrict__ W,
                                                    const int* __restrict__ knn,
                                                    const float* __restrict__ out /* n_p */,
                                                    float* __restrict__ ymax,
                                                    float* __restrict__ ymin,
                                                    float* __restrict__ partials)
{
    __shared__ float Wt[CFEAT][COUT];
    __shared__ float ft[CPB][NS][CFEAT];
    __shared__ float bsum[CPB][COUT], bssq[CPB][COUT];

    const int t = threadIdx.x;
    const int mbase = blockIdx.x * CPB;

    for (int c = 0; c < CFEAT; ++c) Wt[c][t] = W[t*CFEAT + c];

    {
        int r = t >> 1, half = t & 1;
        int ci = r >> 4, s = r & 15;
        int m = mbase + ci;
        int nb = knn[m*NS + s];
        if (half == 0) {
            ft[ci][s][0] = __fsub_rn(p[nb*3+0], out[m*3+0]);
            ft[ci][s][1] = __fsub_rn(p[nb*3+1], out[m*3+1]);
            ft[ci][s][2] = __fsub_rn(p[nb*3+2], out[m*3+2]);
        }
        for (int c = half*32; c < half*32 + 32; ++c)
            ft[ci][s][3+c] = xf[nb*CIN + c];
    }
    __syncthreads();

    const int ci = t >> 5, l = t & 31;
    float acc[NS][4];
#pragma unroll
    for (int s = 0; s < NS; ++s) { acc[s][0]=0.f; acc[s][1]=0.f; acc[s][2]=0.f; acc[s][3]=0.f; }

    for (int c = 0; c < CFEAT; ++c) {
        float w0 = Wt[c][l], w1 = Wt[c][l+32], w2 = Wt[c][l+64], w3 = Wt[c][l+96];
#pragma unroll
        for (int s = 0; s < NS; ++s) {
            float f = ft[ci][s][c];
            acc[s][0] = fmaf(f, w0, acc[s][0]);
            acc[s][1] = fmaf(f, w1, acc[s][1]);
            acc[s][2] = fmaf(f, w2, acc[s][2]);
            acc[s][3] = fmaf(f, w3, acc[s][3]);
        }
    }

    const int m = mbase + ci;
#pragma unroll
    for (int j = 0; j < 4; ++j) {
        int o = l + 32*j;
        float s = 0.f, q = 0.f, mx = -1e30f, mn = 1e30f;
#pragma unroll
        for (int sidx = 0; sidx < NS; ++sidx) {
            float v = acc[sidx][j];
            s += v; q = fmaf(v, v, q);
            mx = fmaxf(mx, v); mn = fminf(mn, v);
        }
        bsum[ci][o] = s;
        bssq[ci][o] = q;
        ymax[m*COUT + o] = mx;
        ymin[m*COUT + o] = mn;
    }
    __syncthreads();
    if (t < COUT) {
        float s = bsum[0][t] + bsum[1][t] + bsum[2][t] + bsum[3][t];
        float q = bssq[0][t] + bssq[1][t] + bssq[2][t] + bssq[3][t];
        partials[t*1024          + blockIdx.x] = s;
        partials[(COUT + t)*1024 + blockIdx.x] = q;
    }
}

// ---------------- BN stats reduce -> scale/shift ----------------
__global__ __launch_bounds__(256) void bnstat_kernel(const float* __restrict__ partials,
                                                     const float* __restrict__ gamma,
                                                     const float* __restrict__ beta,
                                                     float* __restrict__ scaleshift)
{
    __shared__ float red[256];
    int t = threadIdx.x;
    const float4* v4 = (const float4*)(partials + t*1024);
    float s = 0.f;
    for (int i = 0; i < 256; ++i) {
        float4 v = v4[i];
        s += v.x; s += v.y; s += v.z; s += v.w;
    }
    red[t] = s;
    __syncthreads();
    if (t < COUT) {
        const float inv = 1.0f / 65536.0f;
        float mean = red[t] * inv;
        float var  = red[COUT + t] * inv - mean*mean;
        float rstd = rsqrtf(var + 1e-5f);
        float g = gamma[t] * rstd;
        scaleshift[t]        = g;
        scaleshift[COUT + t] = beta[t] - mean * g;
    }
}

// ---------------- final: BN apply + ReLU on the pooled extreme ----------------
__global__ void final_kernel(float* __restrict__ y,
                             const float* __restrict__ ymin,
                             const float* __restrict__ scaleshift)
{
    int i = blockIdx.x * blockDim.x + threadIdx.x;
    if (i >= M_CTR * COUT) return;
    int o = i & (COUT - 1);
    float a = scaleshift[o], b = scaleshift[COUT + o];
    float v = (a >= 0.f) ? y[i] : ymin[i];
    float z = fmaf(a, v, b);
    y[i] = fmaxf(z, 0.f);
}

extern "C" void kernel_launch(void* const* d_in, const int* in_sizes, int n_in,
                              void* d_out, int out_size, void* d_ws, size_t ws_size,
                              hipStream_t stream)
{
    const float* p     = (const float*)d_in[0];
    const float* nrm   = (const float*)d_in[1];
    const float* xf    = (const float*)d_in[2];
    // d_in[3] = o (unused: single batch, static sizes)
    const float* W     = (const float*)d_in[4];
    const float* gamma = (const float*)d_in[5];
    const float* beta  = (const float*)d_in[6];

    float* out = (float*)d_out;
    char* ws = (char*)d_ws;
    int*   sel        = (int*)(ws + 0);            // 16 KB
    float* pp2        = (float*)(ws + 16384);      // 64 KB
    int*   knn        = (int*)(ws + 81920);        // 256 KB (overlaid by sp during FPS)
    float* ymin       = (float*)(ws + 344064);     // 2 MB  (head overlaid by FPS scratch)
    float* partials   = (float*)(ws + 2441216);    // 1 MB
    float* scaleshift = (float*)(ws + 3489792);    // 1 KB

    // FPS scratch overlays (consumed before their hosts are written):
    float4*   sp        = (float4*)(ws + 81920);            // 256 KB in knn region
    char*     yb        = ws + 344064;                      // ymin region
    int*      c_of      = (int*)(yb + 65536);               // 64 KB
    int*      cellcnt   = (int*)(yb + 131072);              // 2 KB
    int*      cellfill  = (int*)(yb + 133120);              // 2 KB
    int*      cellstart = (int*)(yb + 135168);              // 2 KB
    unsigned* bbmin_u   = (unsigned*)(yb + 137216);         // 6 KB
    unsigned* bbmax_u   = (unsigned*)(yb + 143360);         // 6 KB
    float*    gbb       = (float*)(yb + 149504);            // 24 B
    int*      cmeta_g   = (int*)(yb + 149536);              // 2 KB

    float* ymax = out + 24576;  // y region of d_out

    init_kernel   <<<8,  256, 0, stream>>>(bbmin_u, bbmax_u, cellcnt, cellfill);
    bbox_kernel   <<<1,  256, 0, stream>>>(p, gbb);
    assign_kernel <<<64, 256, 0, stream>>>(p, gbb, c_of, cellcnt);
    prefix_kernel <<<1,  512, 0, stream>>>(cellcnt, cellstart, cmeta_g);
    scatter_kernel<<<64, 256, 0, stream>>>(p, c_of, cellstart, cellfill, sp, bbmin_u, bbmax_u);
    fps_kernel    <<<1,  1024, 0, stream>>>(p, sp, cmeta_g, bbmin_u, bbmax_u, sel);
    prep_kernel   <<<64, 256, 0, stream>>>(p, nrm, sel, pp2, out);
    knn_kernel    <<<1024, 256, 0, stream>>>(p, pp2, out, knn);
    passA_kernel  <<<M_CTR/CPB, 128, 0, stream>>>(p, xf, W, knn, out, ymax, ymin, partials);
    bnstat_kernel <<<1, 256, 0, stream>>>(partials, gamma, beta, scaleshift);
    final_kernel  <<<2048, 256, 0, stream>>>(ymax, ymin, scaleshift);
}

// Round 17
// 6408.530 us; speedup vs baseline: 2.6715x; 1.0856x over previous
//
#include <hip/hip_runtime.h>
#include <math.h>

#define N_PTS 16384
#define M_CTR 4096
#define NS 16
#define CIN 64
#define COUT 128
#define CFEAT 67
#define CPB 4          // centers per block in passA
#define NCELL 512      // 8x8x8 grid

typedef unsigned long long u64;

// order-preserving float<->uint transform (for atomic min/max on floats)
__device__ __forceinline__ unsigned ordu(float f) {
    unsigned b = __float_as_uint(f);
    return (b & 0x80000000u) ? ~b : (b | 0x80000000u);
}
__device__ __forceinline__ float unord(unsigned u) {
    unsigned b = (u & 0x80000000u) ? (u & 0x7FFFFFFFu) : ~u;
    return __uint_as_float(b);
}

// sorted-pair merge: (a1>=a2) U (b1>=b2) -> exact top-2 in (a1,a2)
__device__ __forceinline__ void pmerge(u64& a1, u64& a2, u64 b1, u64 b2) {
    u64 n1 = a1 > b1 ? a1 : b1;
    u64 lo = a1 > b1 ? b1 : a1;
    u64 m2 = a2 > b2 ? a2 : b2;
    a2 = lo > m2 ? lo : m2;
    a1 = n1;
}

// top-2 u64 merge via DPP (old=0 = identity for max)
#define DPP_TOP2(CTRL) do { \
    unsigned _o1lo = (unsigned)__builtin_amdgcn_update_dpp(0, (int)(unsigned)k1, CTRL, 0xF, 0xF, false); \
    unsigned _o1hi = (unsigned)__builtin_amdgcn_update_dpp(0, (int)(unsigned)(k1>>32), CTRL, 0xF, 0xF, false); \
    unsigned _o2lo = (unsigned)__builtin_amdgcn_update_dpp(0, (int)(unsigned)k2, CTRL, 0xF, 0xF, false); \
    unsigned _o2hi = (unsigned)__builtin_amdgcn_update_dpp(0, (int)(unsigned)(k2>>32), CTRL, 0xF, 0xF, false); \
    u64 _b1 = ((u64)_o1hi << 32) | (u64)_o1lo; \
    u64 _b2 = ((u64)_o2hi << 32) | (u64)_o2lo; \
    pmerge(k1, k2, _b1, _b2); \
} while (0)

#define DPP_SWEEP64 DPP_TOP2(0x111); DPP_TOP2(0x112); DPP_TOP2(0x114); \
                    DPP_TOP2(0x118); DPP_TOP2(0x142); DPP_TOP2(0x143)

// ---------------- init: counters, bbox atoms ----------------
__global__ void init_kernel(unsigned* __restrict__ bmin, unsigned* __restrict__ bmax,
                            int* __restrict__ cnt, int* __restrict__ fill)
{
    int i = blockIdx.x * blockDim.x + threadIdx.x;
    if (i < NCELL * 3) { bmin[i] = 0xFFFFFFFFu; bmax[i] = 0u; }
    if (i < NCELL) { cnt[i] = 0; fill[i] = 0; }
}

// ---------------- cloud bbox (single block, deterministic) ----------------
__global__ __launch_bounds__(256) void bbox_kernel(const float* __restrict__ p,
                                                   float* __restrict__ gbb)
{
    int t = threadIdx.x, lane = t & 63, w = t >> 6;
    float mnx = 1e30f, mny = 1e30f, mnz = 1e30f;
    float mxx = -1e30f, mxy = -1e30f, mxz = -1e30f;
    for (int i = t; i < N_PTS; i += 256) {
        float x = p[i*3], y = p[i*3+1], z = p[i*3+2];
        mnx = fminf(mnx, x); mny = fminf(mny, y); mnz = fminf(mnz, z);
        mxx = fmaxf(mxx, x); mxy = fmaxf(mxy, y); mxz = fmaxf(mxz, z);
    }
    for (int m = 1; m < 64; m <<= 1) {
        mnx = fminf(mnx, __shfl_xor(mnx, m)); mny = fminf(mny, __shfl_xor(mny, m));
        mnz = fminf(mnz, __shfl_xor(mnz, m));
        mxx = fmaxf(mxx, __shfl_xor(mxx, m)); mxy = fmaxf(mxy, __shfl_xor(mxy, m));
        mxz = fmaxf(mxz, __shfl_xor(mxz, m));
    }
    __shared__ float s[4][6];
    if (lane == 0) { s[w][0]=mnx; s[w][1]=mny; s[w][2]=mnz; s[w][3]=mxx; s[w][4]=mxy; s[w][5]=mxz; }
    __syncthreads();
    if (t == 0) {
        gbb[0] = fminf(fminf(s[0][0], s[1][0]), fminf(s[2][0], s[3][0]));
        gbb[1] = fminf(fminf(s[0][1], s[1][1]), fminf(s[2][1], s[3][1]));
        gbb[2] = fminf(fminf(s[0][2], s[1][2]), fminf(s[2][2], s[3][2]));
        gbb[3] = fmaxf(fmaxf(s[0][3], s[1][3]), fmaxf(s[2][3], s[3][3]));
        gbb[4] = fmaxf(fmaxf(s[0][4], s[1][4]), fmaxf(s[2][4], s[3][4]));
        gbb[5] = fmaxf(fmaxf(s[0][5], s[1][5]), fmaxf(s[2][5], s[3][5]));
    }
}

// ---------------- assign points to cells ----------------
__global__ void assign_kernel(const float* __restrict__ p, const float* __restrict__ gbb,
                              int* __restrict__ c_of, int* __restrict__ cnt)
{
    int i = blockIdx.x * blockDim.x + threadIdx.x;
    if (i >= N_PTS) return;
    float bx = gbb[0], by = gbb[1], bz = gbb[2];
    float sx = 7.9999f / fmaxf(gbb[3] - bx, 1e-20f);
    float sy = 7.9999f / fmaxf(gbb[4] - by, 1e-20f);
    float sz = 7.9999f / fmaxf(gbb[5] - bz, 1e-20f);
    float x = p[i*3], y = p[i*3+1], z = p[i*3+2];
    int ix = min(7, max(0, (int)((x - bx) * sx)));
    int iy = min(7, max(0, (int)((y - by) * sy)));
    int iz = min(7, max(0, (int)((z - bz) * sz)));
    int c = (ix << 6) | (iy << 3) | iz;
    c_of[i] = c;
    atomicAdd(&cnt[c], 1);
}

// ---------------- exclusive prefix over 512 counts + packed meta ----------------
__global__ __launch_bounds__(512) void prefix_kernel(const int* __restrict__ cnt,
                                                     int* __restrict__ start,
                                                     int* __restrict__ cmeta)
{
    __shared__ int a[NCELL];
    int t = threadIdx.x;
    int v = cnt[t]; a[t] = v; __syncthreads();
    for (int off = 1; off < NCELL; off <<= 1) {
        int u = (t >= off) ? a[t - off] : 0;
        __syncthreads();
        a[t] += u;
        __syncthreads();
    }
    int st = a[t] - v;
    start[t] = st;
    cmeta[t] = (st << 15) | v;
}

// ---------------- scatter into sorted order + per-cell tight bbox ----------------
__global__ void scatter_kernel(const float* __restrict__ p, const int* __restrict__ c_of,
                               const int* __restrict__ start, int* __restrict__ fill,
                               float4* __restrict__ sp, unsigned* __restrict__ bmin,
                               unsigned* __restrict__ bmax)
{
    int i = blockIdx.x * blockDim.x + threadIdx.x;
    if (i >= N_PTS) return;
    int c = c_of[i];
    int pos = start[c] + atomicAdd(&fill[c], 1);
    float x = p[i*3], y = p[i*3+1], z = p[i*3+2];
    sp[pos] = make_float4(x, y, z, __int_as_float(i));
    atomicMin(&bmin[c*3+0], ordu(x)); atomicMax(&bmax[c*3+0], ordu(x));
    atomicMin(&bmin[c*3+1], ordu(y)); atomicMax(&bmax[c*3+1], ordu(y));
    atomicMin(&bmin[c*3+2], ordu(z)); atomicMax(&bmax[c*3+2], ordu(z));
}

// ---------------- FPS: pruned, exact, lane-minimal machinery (r11) ----------------
__global__ __launch_bounds__(1024) void fps_kernel(const float* __restrict__ p,
                                                   const float4* __restrict__ sp,
                                                   const int* __restrict__ g_cmeta,
                                                   const unsigned* __restrict__ g_bmin,
                                                   const unsigned* __restrict__ g_bmax,
                                                   int* __restrict__ sel)
{
    __shared__ float distl[N_PTS];                // 64 KB
    __shared__ u64 key1[NCELL], key2[NCELL];      // 8 KB exact per-cell top-2 (persistent)
    __shared__ int cmeta_s[NCELL];                // 2 KB
    __shared__ unsigned short wl[NCELL];          // 1 KB active cells
    __shared__ float bq[6];
    __shared__ int bnsel;
    __shared__ int wlc;

    const int t = threadIdx.x;
    const int lane = t & 63, wave = t >> 6;

    for (int i = t; i < N_PTS; i += 1024) distl[i] = 1e10f;

    int my_cnt = 0;
    float mnx=0.f, mny=0.f, mnz=0.f, mxx=0.f, mxy=0.f, mxz=0.f;
    if (t < NCELL) {
        int meta = g_cmeta[t];
        cmeta_s[t] = meta;
        my_cnt = meta & 0x7FFF;
        mnx = unord(g_bmin[t*3+0]); mny = unord(g_bmin[t*3+1]); mnz = unord(g_bmin[t*3+2]);
        mxx = unord(g_bmax[t*3+0]); mxy = unord(g_bmax[t*3+1]); mxz = unord(g_bmax[t*3+2]);
        key1[t] = 0ull; key2[t] = 0ull;
    }
    if (t == 0) { wlc = 0; sel[0] = 0; }
    float q1x = p[0], q1y = p[1], q1z = p[2];
    float q2x = 0.f, q2y = 0.f, q2z = 0.f;
    bool two = false;
    bool first = true;
    __syncthreads();

    int it = 1;
    while (it < M_CTR) {
        // ---- phase 1: prune (f32, registers + one LDS key read) + ballot append
        bool act = false;
        if (my_cnt > 0) {
            if (first) act = true;
            else {
                float cm = __uint_as_float((unsigned)(key1[t] >> 32)) * 1.00001f;
                float ddx = fmaxf(fmaxf(__fsub_rn(mnx, q1x), __fsub_rn(q1x, mxx)), 0.f);
                float ddy = fmaxf(fmaxf(__fsub_rn(mny, q1y), __fsub_rn(q1y, mxy)), 0.f);
                float ddz = fmaxf(fmaxf(__fsub_rn(mnz, q1z), __fsub_rn(q1z, mxz)), 0.f);
                float dm1 = __fadd_rn(__fadd_rn(__fmul_rn(ddx,ddx), __fmul_rn(ddy,ddy)),
                                      __fmul_rn(ddz,ddz));
                act = dm1 < cm;
                if (!act && two) {
                    float ex = fmaxf(fmaxf(__fsub_rn(mnx, q2x), __fsub_rn(q2x, mxx)), 0.f);
                    float ey = fmaxf(fmaxf(__fsub_rn(mny, q2y), __fsub_rn(q2y, mxy)), 0.f);
                    float ez = fmaxf(fmaxf(__fsub_rn(mnz, q2z), __fsub_rn(q2z, mxz)), 0.f);
                    float dm2 = __fadd_rn(__fadd_rn(__fmul_rn(ex,ex), __fmul_rn(ey,ey)),
                                          __fmul_rn(ez,ez));
                    act = dm2 < cm;
                }
            }
        }
        unsigned long long mask = __ballot(act);
        int base = 0;
        if (lane == 0 && mask) base = atomicAdd(&wlc, (int)__popcll(mask));
        base = __shfl(base, 0);
        if (act)
            wl[base + (int)__popcll(mask & ((1ull << lane) - 1ull))] = (unsigned short)t;
        __syncthreads();
        const int nwl = wlc;

        // ---- phase 2: one wave per active cell; exact cell top-2 written in place
        for (int e = wave; e < nwl; e += 16) {
            int c = wl[e];
            int mv = cmeta_s[c];
            int st = mv >> 15, cnt = mv & 0x7FFF;
            u64 k1 = 0ull, k2 = 0ull;
            for (int o = lane; o < cnt; o += 64) {
                int g = st + o;
                float4 P = sp[g];
                float D = distl[g];
                float dx = __fsub_rn(P.x, q1x), dy = __fsub_rn(P.y, q1y), dz = __fsub_rn(P.z, q1z);
                float d2 = __fadd_rn(__fadd_rn(__fmul_rn(dx,dx), __fmul_rn(dy,dy)),
                                     __fmul_rn(dz,dz));
                float nd = fminf(D, d2);
                if (two) {
                    float ex = __fsub_rn(P.x, q2x), ey = __fsub_rn(P.y, q2y), ez = __fsub_rn(P.z, q2z);
                    float e2 = __fadd_rn(__fadd_rn(__fmul_rn(ex,ex), __fmul_rn(ey,ey)),
                                         __fmul_rn(ez,ez));
                    nd = fminf(nd, e2);
                }
                distl[g] = nd;
                u64 kk = ((u64)__float_as_uint(nd) << 32)
                       | (u64)(~(unsigned)__float_as_int(P.w));
                if (kk > k1) { k2 = k1; k1 = kk; }
                else if (kk > k2) { k2 = kk; }
            }
            DPP_SWEEP64;                 // lane63 = exact cell top-2
            if (lane == 63) { key1[c] = k1; key2[c] = k2; }
        }
        if (t == 1023) wlc = 0;   // safe: wlc unused until next round's append
        __syncthreads();

        // ---- phase 3: wave 0 only — global top-2, accept test, q fetch, broadcast
        if (wave == 0) {
            u64 k1 = 0ull, k2 = 0ull;
#pragma unroll
            for (int j = 0; j < 8; ++j) {
                int c = lane + (j << 6);
                pmerge(k1, k2, key1[c], key2[c]);
            }
            DPP_SWEEP64;
            if (lane == 63) {
                u64 A1 = k1, A2 = k2;
                int s1 = (int)(~(unsigned)(A1 & 0xFFFFFFFFull));
                int s2 = (int)(~(unsigned)(A2 & 0xFFFFFFFFull));
                sel[it] = s1;
                float nq1x = p[s1*3+0], nq1y = p[s1*3+1], nq1z = p[s1*3+2];
                float bx2 = p[s2*3+0], by2 = p[s2*3+1], bz2 = p[s2*3+2];
                int nsel = 1;
                if (A2 != 0ull && it + 1 < M_CTR) {
                    // exact: if s1's update leaves the global #2 key unchanged,
                    // every other key can only drop below it -> s2 is next pick.
                    float dx = __fsub_rn(bx2, nq1x), dy = __fsub_rn(by2, nq1y), dz = __fsub_rn(bz2, nq1z);
                    float d2b = __fadd_rn(__fadd_rn(__fmul_rn(dx,dx), __fmul_rn(dy,dy)),
                                          __fmul_rn(dz,dz));
                    float db = __uint_as_float((unsigned)(A2 >> 32));
                    if (d2b >= db) { nsel = 2; sel[it + 1] = s2; }
                }
                bq[0] = nq1x; bq[1] = nq1y; bq[2] = nq1z;
                bq[3] = bx2;  bq[4] = by2;  bq[5] = bz2;
                bnsel = nsel;
            }
        }
        __syncthreads();
        int nsel = bnsel;
        q1x = bq[0]; q1y = bq[1]; q1z = bq[2];
        two = (nsel == 2);
        if (two) { q2x = bq[3]; q2y = bq[4]; q2z = bq[5]; }
        first = false;
        it += nsel;
    }
}

// ---------------- prep: pp2, gather n_p/n_n, write n_o ----------------
__global__ void prep_kernel(const float* __restrict__ p, const float* __restrict__ nrm,
                            const int* __restrict__ sel, float* __restrict__ pp2,
                            float* __restrict__ out)
{
    int i = blockIdx.x * blockDim.x + threadIdx.x;
    if (i < N_PTS) {
        float x = p[i*3], y = p[i*3+1], z = p[i*3+2];
        pp2[i] = __fadd_rn(__fadd_rn(__fmul_rn(x,x), __fmul_rn(y,y)), __fmul_rn(z,z));
    }
    if (i < M_CTR) {
        int j = sel[i];
        out[i*3+0] = p[j*3+0]; out[i*3+1] = p[j*3+1]; out[i*3+2] = p[j*3+2];
        out[12288 + i*3+0] = nrm[j*3+0];
        out[12288 + i*3+1] = nrm[j*3+1];
        out[12288 + i*3+2] = nrm[j*3+2];
    }
    if (i == 0) out[548864] = (float)M_CTR;   // n_o
}

// ---------------- kNN: one wave per center, per-lane sorted top-16 ----------------
__global__ __launch_bounds__(256) void knn_kernel(const float* __restrict__ p,
                                                  const float* __restrict__ pp2,
                                                  const float* __restrict__ np /* n_p */,
                                                  int* __restrict__ knn)
{
    const int lane = threadIdx.x & 63;
    const int wave = threadIdx.x >> 6;
    const int c = blockIdx.x * 4 + wave;

    float cx = np[c*3], cy = np[c*3+1], cz = np[c*3+2];
    float c2 = __fadd_rn(__fadd_rn(__fmul_rn(cx,cx), __fmul_rn(cy,cy)), __fmul_rn(cz,cz));

    float hd[16]; int hi[16];
#pragma unroll
    for (int k = 0; k < 16; ++k) { hd[k] = 1e30f; hi[k] = 0x7fffffff; }

    for (int t = 0; t < N_PTS/64; ++t) {
        int j = t*64 + lane;
        float px = p[j*3+0], py = p[j*3+1], pz = p[j*3+2];
        float dot = __fadd_rn(__fadd_rn(__fmul_rn(cx,px), __fmul_rn(cy,py)),
                              __fmul_rn(cz,pz));
        float d2  = __fsub_rn(__fadd_rn(c2, pp2[j]), __fmul_rn(2.0f, dot));
        if (d2 < hd[15]) {
#pragma unroll
            for (int k = 15; k >= 1; --k) {
                bool up   = d2 < hd[k-1];
                bool here = d2 < hd[k];
                hd[k] = up ? hd[k-1] : (here ? d2 : hd[k]);
                hi[k] = up ? hi[k-1] : (here ? j  : hi[k]);
            }
            if (d2 < hd[0]) { hd[0] = d2; hi[0] = j; }
        }
    }

    for (int r = 0; r < 16; ++r) {
        float wv = hd[0]; int wi = hi[0];
#pragma unroll
        for (int m = 1; m < 64; m <<= 1) {
            float ov = __shfl_xor(wv, m);
            int   oi = __shfl_xor(wi, m);
            bool b = (ov < wv) || (ov == wv && oi < wi);
            wv = b ? ov : wv; wi = b ? oi : wi;
        }
        if (hi[0] == wi) {
            knn[c*16 + r] = wi;
#pragma unroll
            for (int k = 0; k < 15; ++k) { hd[k] = hd[k+1]; hi[k] = hi[k+1]; }
            hd[15] = 1e30f; hi[15] = 0x7fffffff;
        }
    }
}

// ---------------- pass A: feat build + GEMM + stats + ymax/ymin ----------------
__global__ __launch_bounds__(128) void passA_kernel(const float* __restrict__ p,
                                                    const float* __restrict__ xf,
                                                    const float* __restrict__ W,
                                                    const int* __restrict__ knn,
                                                    const float* __restrict__ out /* n_p */,
                                                    float* __restrict__ ymax,
                                                    float* __restrict__ ymin,
                                                    float* __restrict__ partials)
{
    __shared__ float Wt[CFEAT][COUT];
    __shared__ float ft[CPB][NS][CFEAT];
    __shared__ float bsum[CPB][COUT], bssq[CPB][COUT];

    const int t = threadIdx.x;
    const int mbase = blockIdx.x * CPB;

    for (int c = 0; c < CFEAT; ++c) Wt[c][t] = W[t*CFEAT + c];

    {
        int r = t >> 1, half = t & 1;
        int ci = r >> 4, s = r & 15;
        int m = mbase + ci;
        int nb = knn[m*NS + s];
        if (half == 0) {
            ft[ci][s][0] = __fsub_rn(p[nb*3+0], out[m*3+0]);
            ft[ci][s][1] = __fsub_rn(p[nb*3+1], out[m*3+1]);
            ft[ci][s][2] = __fsub_rn(p[nb*3+2], out[m*3+2]);
        }
        for (int c = half*32; c < half*32 + 32; ++c)
            ft[ci][s][3+c] = xf[nb*CIN + c];
    }
    __syncthreads();

    const int ci = t >> 5, l = t & 31;
    float acc[NS][4];
#pragma unroll
    for (int s = 0; s < NS; ++s) { acc[s][0]=0.f; acc[s][1]=0.f; acc[s][2]=0.f; acc[s][3]=0.f; }

    for (int c = 0; c < CFEAT; ++c) {
        float w0 = Wt[c][l], w1 = Wt[c][l+32], w2 = Wt[c][l+64], w3 = Wt[c][l+96];
#pragma unroll
        for (int s = 0; s < NS; ++s) {
            float f = ft[ci][s][c];
            acc[s][0] = fmaf(f, w0, acc[s][0]);
            acc[s][1] = fmaf(f, w1, acc[s][1]);
            acc[s][2] = fmaf(f, w2, acc[s][2]);
            acc[s][3] = fmaf(f, w3, acc[s][3]);
        }
    }

    const int m = mbase + ci;
#pragma unroll
    for (int j = 0; j < 4; ++j) {
        int o = l + 32*j;
        float s = 0.f, q = 0.f, mx = -1e30f, mn = 1e30f;
#pragma unroll
        for (int sidx = 0; sidx < NS; ++sidx) {
            float v = acc[sidx][j];
            s += v; q = fmaf(v, v, q);
            mx = fmaxf(mx, v); mn = fminf(mn, v);
        }
        bsum[ci][o] = s;
        bssq[ci][o] = q;
        ymax[m*COUT + o] = mx;
        ymin[m*COUT + o] = mn;
    }
    __syncthreads();
    if (t < COUT) {
        float s = bsum[0][t] + bsum[1][t] + bsum[2][t] + bsum[3][t];
        float q = bssq[0][t] + bssq[1][t] + bssq[2][t] + bssq[3][t];
        partials[t*1024          + blockIdx.x] = s;
        partials[(COUT + t)*1024 + blockIdx.x] = q;
    }
}

// ---------------- BN stats reduce -> scale/shift ----------------
__global__ __launch_bounds__(256) void bnstat_kernel(const float* __restrict__ partials,
                                                     const float* __restrict__ gamma,
                                                     const float* __restrict__ beta,
                                                     float* __restrict__ scaleshift)
{
    __shared__ float red[256];
    int t = threadIdx.x;
    const float4* v4 = (const float4*)(partials + t*1024);
    float s = 0.f;
    for (int i = 0; i < 256; ++i) {
        float4 v = v4[i];
        s += v.x; s += v.y; s += v.z; s += v.w;
    }
    red[t] = s;
    __syncthreads();
    if (t < COUT) {
        const float inv = 1.0f / 65536.0f;
        float mean = red[t] * inv;
        float var  = red[COUT + t] * inv - mean*mean;
        float rstd = rsqrtf(var + 1e-5f);
        float g = gamma[t] * rstd;
        scaleshift[t]        = g;
        scaleshift[COUT + t] = beta[t] - mean * g;
    }
}

// ---------------- final: BN apply + ReLU on the pooled extreme ----------------
__global__ void final_kernel(float* __restrict__ y,
                             const float* __restrict__ ymin,
                             const float* __restrict__ scaleshift)
{
    int i = blockIdx.x * blockDim.x + threadIdx.x;
    if (i >= M_CTR * COUT) return;
    int o = i & (COUT - 1);
    float a = scaleshift[o], b = scaleshift[COUT + o];
    float v = (a >= 0.f) ? y[i] : ymin[i];
    float z = fmaf(a, v, b);
    y[i] = fmaxf(z, 0.f);
}

extern "C" void kernel_launch(void* const* d_in, const int* in_sizes, int n_in,
                              void* d_out, int out_size, void* d_ws, size_t ws_size,
                              hipStream_t stream)
{
    const float* p     = (const float*)d_in[0];
    const float* nrm   = (const float*)d_in[1];
    const float* xf    = (const float*)d_in[2];
    // d_in[3] = o (unused: single batch, static sizes)
    const float* W     = (const float*)d_in[4];
    const float* gamma = (const float*)d_in[5];
    const float* beta  = (const float*)d_in[6];

    float* out = (float*)d_out;
    char* ws = (char*)d_ws;
    int*   sel        = (int*)(ws + 0);            // 16 KB
    float* pp2        = (float*)(ws + 16384);      // 64 KB
    int*   knn        = (int*)(ws + 81920);        // 256 KB (overlaid by sp during FPS)
    float* ymin       = (float*)(ws + 344064);     // 2 MB  (head overlaid by FPS scratch)
    float* partials   = (float*)(ws + 2441216);    // 1 MB
    float* scaleshift = (float*)(ws + 3489792);    // 1 KB

    // FPS scratch overlays (consumed before their hosts are written):
    float4*   sp        = (float4*)(ws + 81920);            // 256 KB in knn region
    char*     yb        = ws + 344064;                      // ymin region
    int*      c_of      = (int*)(yb + 65536);               // 64 KB
    int*      cellcnt   = (int*)(yb + 131072);              // 2 KB
    int*      cellfill  = (int*)(yb + 133120);              // 2 KB
    int*      cellstart = (int*)(yb + 135168);              // 2 KB
    unsigned* bbmin_u   = (unsigned*)(yb + 137216);         // 6 KB
    unsigned* bbmax_u   = (unsigned*)(yb + 143360);         // 6 KB
    float*    gbb       = (float*)(yb + 149504);            // 24 B
    int*      cmeta_g   = (int*)(yb + 149536);              // 2 KB

    float* ymax = out + 24576;  // y region of d_out

    init_kernel   <<<8,  256, 0, stream>>>(bbmin_u, bbmax_u, cellcnt, cellfill);
    bbox_kernel   <<<1,  256, 0, stream>>>(p, gbb);
    assign_kernel <<<64, 256, 0, stream>>>(p, gbb, c_of, cellcnt);
    prefix_kernel <<<1,  512, 0, stream>>>(cellcnt, cellstart, cmeta_g);
    scatter_kernel<<<64, 256, 0, stream>>>(p, c_of, cellstart, cellfill, sp, bbmin_u, bbmax_u);
    fps_kernel    <<<1,  1024, 0, stream>>>(p, sp, cmeta_g, bbmin_u, bbmax_u, sel);
    prep_kernel   <<<64, 256, 0, stream>>>(p, nrm, sel, pp2, out);
    knn_kernel    <<<1024, 256, 0, stream>>>(p, pp2, out, knn);
    passA_kernel  <<<M_CTR/CPB, 128, 0, stream>>>(p, xf, W, knn, out, ymax, ymin, partials);
    bnstat_kernel <<<1, 256, 0, stream>>>(partials, gamma, beta, scaleshift);
    final_kernel  <<<2048, 256, 0, stream>>>(ymax, ymin, scaleshift);
}